// Round 12
// baseline (340.521 us; speedup 1.0000x reference)
//
#include <hip/hip_runtime.h>
#include <cstdint>

using h8v = __attribute__((ext_vector_type(8))) _Float16;
using h4v = __attribute__((ext_vector_type(4))) _Float16;
using f4v = __attribute__((ext_vector_type(4))) float;

__device__ __forceinline__ float sigmoidf_(float x) {
  return 1.0f / (1.0f + __expf(-x));
}
__device__ __forceinline__ float tanhf_(float x) {
  return 2.0f / (1.0f + __expf(-2.0f * x)) - 1.0f;
}

#define BN 256       // nodes per bucket
#define BCAP 4096    // LDS edge buffer cap (raw avg 2560, padded avg ~3460)
#define NBMAX 1024   // max buckets (N <= 262144)

// h16a[i][j] = emb[x[i]][j]; row N of BOTH planes = 0 (pad target row)
__global__ __launch_bounds__(256) void k_embed(const int* __restrict__ x,
                                               const float* __restrict__ emb,
                                               _Float16* __restrict__ h16a,
                                               _Float16* __restrict__ h16b, int N) {
  int idx = blockIdx.x * 256 + threadIdx.x;
  if (idx >= (N + 1) * 64) return;
  int i = idx >> 6, j = idx & 63;
  if (i < N) {
    h16a[idx] = (_Float16)emb[x[i] * 64 + j];
  } else {
    h16a[idx] = (_Float16)0.0f;
    h16b[idx] = (_Float16)0.0f;
  }
}

// bucket histogram of dst (bucket = dst>>8), LDS-aggregated
__global__ __launch_bounds__(256) void k_hist(const int* __restrict__ dst,
                                              int* __restrict__ hist, int E) {
  __shared__ int lh[NBMAX];
  for (int i = threadIdx.x; i < NBMAX; i += 256) lh[i] = 0;
  __syncthreads();
  for (int e = blockIdx.x * 256 + threadIdx.x; e < E; e += gridDim.x * 256)
    atomicAdd(&lh[dst[e] >> 8], 1);
  __syncthreads();
  for (int i = threadIdx.x; i < NBMAX; i += 256)
    if (lh[i]) atomicAdd(&hist[i], lh[i]);
}

// exclusive scan of hist -> bbase[0..nb]
__global__ __launch_bounds__(1024) void k_bscan(const int* __restrict__ hist,
                                                int* __restrict__ bbase, int nb) {
  __shared__ int sc[NBMAX];
  int t = threadIdx.x;
  int v = (t < nb) ? hist[t] : 0;
  sc[t] = v;
  __syncthreads();
  for (int off = 1; off < NBMAX; off <<= 1) {
    int xx = (t >= off) ? sc[t - off] : 0;
    __syncthreads();
    sc[t] += xx;
    __syncthreads();
  }
  if (t <= nb) bbase[t] = sc[t] - v;  // exclusive (v=0 for t==nb)
}

#define EPB 4096
// scatter edges into bucket-major chunks: ebuf[pos] = (dstLocal<<20) | src
__global__ __launch_bounds__(256) void k_scatter(const int* __restrict__ src,
                                                 const int* __restrict__ dst,
                                                 const int* __restrict__ bbase,
                                                 int* __restrict__ cursor,
                                                 unsigned* __restrict__ ebuf,
                                                 int E, int nb) {
  __shared__ int lh[NBMAX];
  __shared__ int lbase[NBMAX];
  for (int i = threadIdx.x; i < NBMAX; i += 256) lh[i] = 0;
  __syncthreads();
  const int e0 = blockIdx.x * EPB;
  const int e1 = min(e0 + EPB, E);
  for (int e = e0 + threadIdx.x; e < e1; e += 256) atomicAdd(&lh[dst[e] >> 8], 1);
  __syncthreads();
  for (int i = threadIdx.x; i < nb; i += 256) {
    int c = lh[i];
    lbase[i] = c ? (bbase[i] + atomicAdd(&cursor[i], c)) : 0;
    lh[i] = 0;
  }
  __syncthreads();
  for (int e = e0 + threadIdx.x; e < e1; e += 256) {
    int d = dst[e];
    int b = d >> 8;
    int off = atomicAdd(&lh[b], 1);
    ebuf[lbase[b] + off] = ((unsigned)(d & 255) << 20) | (unsigned)src[e];
  }
}

// per-bucket padded CSR: per-node counts, pad to multiple of 8 with src=N
// (zero row), reserve padded region via global cursor, emit rowp/rowe/ssrc.
__global__ __launch_bounds__(256) void k_csr(const unsigned* __restrict__ ebuf,
                                             const int* __restrict__ bbase,
                                             int* __restrict__ padCur,
                                             int* __restrict__ rowp,
                                             int* __restrict__ rowe,
                                             int* __restrict__ ssrc, int N) {
  __shared__ unsigned se[BCAP];
  __shared__ int ss[BCAP];
  __shared__ int cnt[BN], pex[BN], sc[BN];
  __shared__ int sbase;
  const int b = blockIdx.x;
  const int t = threadIdx.x;
  const int nbeg = b * BN;
  const int ebeg = bbase[b];
  int ne = bbase[b + 1] - ebeg;
  if (ne > BCAP) ne = BCAP;  // statistically unreachable
  for (int i = t; i < ne; i += 256) se[i] = ebuf[ebeg + i];
  cnt[t] = 0;
  __syncthreads();
  for (int i = t; i < ne; i += 256) atomicAdd(&cnt[se[i] >> 20], 1);
  __syncthreads();
  const int c = cnt[t];
  const int p = (c + 7) & ~7;  // padded size
  sc[t] = p;
  __syncthreads();
  for (int off = 1; off < BN; off <<= 1) {
    int xx = (t >= off) ? sc[t - off] : 0;
    __syncthreads();
    sc[t] += xx;
    __syncthreads();
  }
  const int pexcl = sc[t] - p;
  const int P = sc[BN - 1];  // padded bucket total
  if (t == 0) sbase = atomicAdd(padCur, P);
  pex[t] = pexcl;
  cnt[t] = 0;
  __syncthreads();
  const int n = nbeg + t;
  if (n < N) {
    rowp[n] = sbase + pexcl;
    rowe[n] = sbase + pexcl + p;
  }
  // pad entries -> zero row N
  for (int i = c; i < p; ++i) ss[pexcl + i] = N;
  // bucket-local sort by node
  for (int i = t; i < ne; i += 256) {
    unsigned e = se[i];
    int dL = e >> 20;
    int off = atomicAdd(&cnt[dL], 1);
    ss[pex[dL] + off] = (int)(e & 0xFFFFF);
  }
  __syncthreads();
  // coalesced writeout
  for (int i = t; i < P; i += 256) ssrc[sbase + i] = ss[i];
}

// All-3-layers Wp fold + fp16 MFMA-fragment pack, gate-major.
// Per layer: idx = (((w*4+g)*4+t)*64+lane)*8+i holds
// B[32t + 8*(lane>>4) + i][gate g, col 16w + (lane&15)],
// B[k][g,j] = (k<64) ? Wp[64g'+j][k] : whh[64g''+j][k-64]
//   g=0: r (Wp j ; whh j),  g=1: z (Wp 64+j ; whh 64+j),
//   g=2: inn (Wp 128+j ; 0),  g=3: hn (0 ; whh 128+j)
// Wp[r][k] = sum_m wih[r][m] * ggc[k][m].
__global__ __launch_bounds__(256) void k_wpack3(const float* __restrict__ wih_all,
                                                const float* __restrict__ ggc_all,
                                                const float* __restrict__ whh_all,
                                                _Float16* __restrict__ Bp) {
  int l = blockIdx.x >> 4;  // layer
  int tid = (blockIdx.x & 15) * 256 + threadIdx.x;
  const float* wih = wih_all + (size_t)l * 192 * 64;
  const float* ggc = ggc_all + (size_t)l * 64 * 64;
  const float* whh = whh_all + (size_t)l * 192 * 64;
  int lane = tid & 63;
  int t = (tid >> 6) & 3;
  int wg = tid >> 8;
  int g = wg & 3, w = wg >> 2;
  int j = 16 * w + (lane & 15);
  int kbase = t * 32 + (lane >> 4) * 8;
  _Float16 hv[8];
#pragma unroll
  for (int i = 0; i < 8; ++i) {
    int k = kbase + i;
    float v = 0.0f;
    if (k < 64) {
      if (g < 3) {
        const float* a = wih + (size_t)(g * 64 + j) * 64;
        const float* bp = ggc + (size_t)k * 64;
        float s = 0.0f;
#pragma unroll
        for (int m = 0; m < 64; ++m) s += a[m] * bp[m];
        v = s;
      }
    } else {
      if (g != 2) {
        int row = (g == 3 ? 2 : g) * 64 + j;
        v = whh[(size_t)row * 64 + (k - 64)];
      }
    }
    hv[i] = (_Float16)v;
  }
  _Float16* o = Bp + (size_t)l * 32768 + (size_t)tid * 8;
#pragma unroll
  for (int i = 0; i < 8; ++i) o[i] = hv[i];
}

__device__ __forceinline__ h8v f32lds_to_h8(const float* __restrict__ p) {
  f4v x0 = *(const f4v*)p;
  f4v x1 = *(const f4v*)(p + 4);
  h8v r;
#pragma unroll
  for (int i = 0; i < 4; ++i) {
    r[i] = (_Float16)x0[i];
    r[4 + i] = (_Float16)x1[i];
  }
  return r;
}

#define FSTRIDE 68  // f32 LDS row stride (64 + 4 pad)
#define HSTRIDE 72  // fp16 LDS row stride (64 + 8 pad)

// Fused CSR-gather + GRU (fp16 MFMA, gate-major, in-register gates),
// fp16-only h plane, coalesced stores via LDS exchange.
// Gather: padded edge lists (multiple of 8, pads -> zero row N), so the
// walk is a single uniform 8-deep loop with no tail.
// (256,8): VGPR cap 64 == what the compiler already allocates; doubles
// the occupancy ceiling for the latency-bound gather.
// last=1: fused mean-pool accumulate instead of h stores.
__global__ __launch_bounds__(256, 8) void k_gfu(const _Float16* __restrict__ hin16,
                                                _Float16* __restrict__ hout16,
                                                const int* __restrict__ rowp,
                                                const int* __restrict__ rowe,
                                                const int* __restrict__ ssrc,
                                                const _Float16* __restrict__ Bp,
                                                const float* __restrict__ bih,
                                                const float* __restrict__ bhh,
                                                const int* __restrict__ batch,
                                                float* __restrict__ psum,
                                                float* __restrict__ pcnt,
                                                int N, int nTiles, int last) {
  __shared__ float aggLds[16 * FSTRIDE];
  __shared__ _Float16 hLds[16 * HSTRIDE];
  __shared__ _Float16 oLds[16 * HSTRIDE];
  const int lane = threadIdx.x & 63;
  const int w = threadIdx.x >> 6;
  const int r15 = lane & 15;
  const int kg8 = (lane >> 4) * 8;
  const int jj = w * 16 + r15;  // this lane's output column

  const float b_r = bih[jj] + bhh[jj];
  const float b_z = bih[64 + jj] + bhh[64 + jj];
  const float b_i = bih[128 + jj];
  const float b_h = bhh[128 + jj];

  // B fragments (zero blocks skipped): g=0,1: t=0..3 ; g=2: t=0,1 ; g=3: t=2,3
  h8v b0[4], b1[4], b2[2], b3[2];
#pragma unroll
  for (int t = 0; t < 4; ++t) {
    b0[t] = *(const h8v*)(Bp + ((size_t)((w * 4 + 0) * 4 + t) * 64 + lane) * 8);
    b1[t] = *(const h8v*)(Bp + ((size_t)((w * 4 + 1) * 4 + t) * 64 + lane) * 8);
  }
#pragma unroll
  for (int t = 0; t < 2; ++t) {
    b2[t] = *(const h8v*)(Bp + ((size_t)((w * 4 + 2) * 4 + t) * 64 + lane) * 8);
    b3[t] = *(const h8v*)(Bp + ((size_t)((w * 4 + 3) * 4 + (2 + t)) * 64 + lane) * 8);
  }

  for (int tile = blockIdx.x; tile < nTiles; tile += gridDim.x) {
    const int n0 = tile * 16;
    __syncthreads();  // prev store phase done before restaging
    // ---- gather + fp16 h staging (each 16-lane group owns a node) ----
    {
      const int g = lane >> 4;
      const int node = 4 * w + g;
      const int n = n0 + node;
      const int nc = min(n, N - 1);
      h4v hv = *(const h4v*)(hin16 + (size_t)nc * 64 + 4 * r15);
      f4v a0 = {0, 0, 0, 0}, a1 = {0, 0, 0, 0}, a2 = {0, 0, 0, 0}, a3 = {0, 0, 0, 0};
      if (n < N) {
        int e = rowp[n];
        const int end = rowe[n];
        // uniform 8-deep loop, no tail (padded lists; pads hit zero row)
        for (; e < end; e += 8) {
          int s0 = ssrc[e], s1 = ssrc[e + 1], s2 = ssrc[e + 2], s3 = ssrc[e + 3];
          int s4 = ssrc[e + 4], s5 = ssrc[e + 5], s6 = ssrc[e + 6], s7 = ssrc[e + 7];
          h4v v0 = *(const h4v*)(hin16 + (size_t)s0 * 64 + 4 * r15);
          h4v v1 = *(const h4v*)(hin16 + (size_t)s1 * 64 + 4 * r15);
          h4v v2 = *(const h4v*)(hin16 + (size_t)s2 * 64 + 4 * r15);
          h4v v3 = *(const h4v*)(hin16 + (size_t)s3 * 64 + 4 * r15);
          h4v v4 = *(const h4v*)(hin16 + (size_t)s4 * 64 + 4 * r15);
          h4v v5 = *(const h4v*)(hin16 + (size_t)s5 * 64 + 4 * r15);
          h4v v6 = *(const h4v*)(hin16 + (size_t)s6 * 64 + 4 * r15);
          h4v v7 = *(const h4v*)(hin16 + (size_t)s7 * 64 + 4 * r15);
          a0 += __builtin_convertvector(v0, f4v);
          a1 += __builtin_convertvector(v1, f4v);
          a2 += __builtin_convertvector(v2, f4v);
          a3 += __builtin_convertvector(v3, f4v);
          a0 += __builtin_convertvector(v4, f4v);
          a1 += __builtin_convertvector(v5, f4v);
          a2 += __builtin_convertvector(v6, f4v);
          a3 += __builtin_convertvector(v7, f4v);
        }
      }
      a0 += a1; a2 += a3; a0 += a2;
      *(f4v*)(aggLds + node * FSTRIDE + 4 * r15) = a0;
      *(h4v*)(hLds + node * HSTRIDE + 4 * r15) = hv;
    }
    __syncthreads();

    // ---- A fragments: t=0,1 from agg (f32->fp16), t=2,3 direct fp16 ----
    h8v ah[4];
#pragma unroll
    for (int t = 0; t < 2; ++t)
      ah[t] = f32lds_to_h8(aggLds + r15 * FSTRIDE + t * 32 + kg8);
#pragma unroll
    for (int t = 0; t < 2; ++t)
      ah[2 + t] = *(const h8v*)(hLds + r15 * HSTRIDE + t * 32 + kg8);

    f4v acc0 = {0, 0, 0, 0}, acc1 = {0, 0, 0, 0}, acc2 = {0, 0, 0, 0}, acc3 = {0, 0, 0, 0};
#pragma unroll
    for (int t = 0; t < 4; ++t) {
      acc0 = __builtin_amdgcn_mfma_f32_16x16x32_f16(ah[t], b0[t], acc0, 0, 0, 0);
      acc1 = __builtin_amdgcn_mfma_f32_16x16x32_f16(ah[t], b1[t], acc1, 0, 0, 0);
    }
    acc2 = __builtin_amdgcn_mfma_f32_16x16x32_f16(ah[0], b2[0], acc2, 0, 0, 0);
    acc2 = __builtin_amdgcn_mfma_f32_16x16x32_f16(ah[1], b2[1], acc2, 0, 0, 0);
    acc3 = __builtin_amdgcn_mfma_f32_16x16x32_f16(ah[2], b3[0], acc3, 0, 0, 0);
    acc3 = __builtin_amdgcn_mfma_f32_16x16x32_f16(ah[3], b3[1], acc3, 0, 0, 0);

    // ---- in-register gates: C row = (lane>>4)*4 + q, col = jj [m89] ----
    const int rb = (lane >> 4) * 4;
#pragma unroll
    for (int q = 0; q < 4; ++q) {
      int row = rb + q;
      float hold = (float)hLds[row * HSTRIDE + jj];
      float r = sigmoidf_(acc0[q] + b_r);
      float z = sigmoidf_(acc1[q] + b_z);
      float nv = tanhf_(acc2[q] + b_i + r * (acc3[q] + b_h));
      float o = (1.0f - z) * nv + z * hold;
      oLds[row * HSTRIDE + jj] = (_Float16)fmaxf(o, 0.0f);
    }
    __syncthreads();

    // ---- store phase ----
    if (!last) {
      // coalesced full-row stores: 16 threads cover one 128B fp16 row
      const int node = threadIdx.x >> 4;
      const int ci = (threadIdx.x & 15) * 4;
      const int n = n0 + node;
      if (n < N) {
        h4v o = *(const h4v*)(oLds + node * HSTRIDE + ci);
        *(h4v*)(hout16 + (size_t)n * 64 + ci) = o;
      }
    } else {
      // fused segment-mean accumulate (batch sorted): wave 0 walks the tile
      if (threadIdx.x < 64) {
        int curb = batch[n0];
        float acc = 0.0f, ca = 0.0f;
#pragma unroll 1
        for (int i = 0; i < 16; ++i) {
          int n = n0 + i;
          if (n >= N) break;
          int b = batch[n];
          if (b != curb) {
            atomicAdd(&psum[curb * 64 + lane], acc);
            if (lane == 0) atomicAdd(&pcnt[curb], ca);
            acc = 0.0f; ca = 0.0f; curb = b;
          }
          acc += (float)oLds[i * HSTRIDE + lane];
          ca += 1.0f;
        }
        atomicAdd(&psum[curb * 64 + lane], acc);
        if (lane == 0) atomicAdd(&pcnt[curb], ca);
      }
    }
  }
}

// MLP head: 64 -> 32 -> 16 -> 1, one 64-thread block per batch element
__global__ __launch_bounds__(64) void k_head(const float* __restrict__ psum,
                                             const float* __restrict__ pcnt,
                                             const float* __restrict__ fc1W,
                                             const float* __restrict__ fc1b,
                                             const float* __restrict__ fc2W,
                                             const float* __restrict__ fc2b,
                                             const float* __restrict__ fc3W,
                                             const float* __restrict__ fc3b,
                                             float* __restrict__ out) {
  int b = blockIdx.x;
  int j = threadIdx.x;
  float c = fmaxf(pcnt[b], 1.0f);
  float p = psum[b * 64 + j] / c;
  int j1 = j & 31;
  float y1 = fc1b[j1];
#pragma unroll
  for (int k = 0; k < 64; ++k) y1 += fc1W[j1 * 64 + k] * __shfl(p, k, 64);
  y1 = fmaxf(y1, 0.0f);
  int j2 = j & 15;
  float y2 = fc2b[j2];
#pragma unroll
  for (int k = 0; k < 32; ++k) y2 += fc2W[j2 * 32 + k] * __shfl(y1, k, 64);
  y2 = fmaxf(y2, 0.0f);
  float y = 0.0f;
#pragma unroll
  for (int k = 0; k < 16; ++k) y += fc3W[k] * __shfl(y2, k, 64);
  if (j == 0) out[b] = y + fc3b[0];
}

extern "C" void kernel_launch(void* const* d_in, const int* in_sizes, int n_in,
                              void* d_out, int out_size, void* d_ws, size_t ws_size,
                              hipStream_t stream) {
  const int N = in_sizes[0];
  const int E = in_sizes[1] / 2;
  const int B = out_size;

  const int* x = (const int*)d_in[0];
  const int* eidx = (const int*)d_in[1];
  const int* batch = (const int*)d_in[3];
  const float* emb = (const float*)d_in[4];
  const float* ggcW = (const float*)d_in[7];
  const float* wih = (const float*)d_in[8];
  const float* whh = (const float*)d_in[9];
  const float* bih = (const float*)d_in[10];
  const float* bhh = (const float*)d_in[11];
  const float* fc1W = (const float*)d_in[12];
  const float* fc1b = (const float*)d_in[13];
  const float* fc2W = (const float*)d_in[14];
  const float* fc2b = (const float*)d_in[15];
  const float* fc3W = (const float*)d_in[16];
  const float* fc3b = (const float*)d_in[17];
  float* out = (float*)d_out;

  const int* srcp = eidx;
  const int* dstp = eidx + E;
  const int nb = (N + BN - 1) / BN;  // buckets

  char* ws = (char*)d_ws;
  size_t off = 0;
  auto alloc = [&](size_t bytes) -> void* {
    void* p = ws + off;
    off = (off + bytes + 255) & ~(size_t)255;
    return p;
  };
  _Float16* h16a = (_Float16*)alloc((size_t)(N + 1) * 64 * 2);
  _Float16* h16b = (_Float16*)alloc((size_t)(N + 1) * 64 * 2);
  int* rowp = (int*)alloc((size_t)(N + 1) * 4);
  int* rowe = (int*)alloc((size_t)(N + 1) * 4);
  int* ssrc = (int*)alloc(((size_t)E + 8 * (size_t)N) * 4);  // padded
  unsigned* ebuf = (unsigned*)alloc((size_t)E * 4);
  int* hist = (int*)alloc((size_t)NBMAX * 4);
  int* bbase = (int*)alloc((size_t)(NBMAX + 1) * 4);
  int* cursor = (int*)alloc((size_t)NBMAX * 4);
  int* padCur = (int*)alloc(256);
  _Float16* Bp = (_Float16*)alloc((size_t)3 * 32768 * 2);
  float* pool = (float*)alloc((size_t)(B * 64 + B) * 4);
  float* psum = pool;
  float* pcnt = pool + (size_t)B * 64;

  // --- bucketed padded-CSR build (coalesced writes) + embed + weight pack ---
  hipMemsetAsync(hist, 0, (size_t)NBMAX * 4, stream);
  hipMemsetAsync(cursor, 0, (size_t)NBMAX * 4, stream);
  hipMemsetAsync(padCur, 0, 256, stream);
  hipMemsetAsync(pool, 0, (size_t)(B * 64 + B) * 4, stream);
  k_embed<<<((N + 1) * 64 + 255) / 256, 256, 0, stream>>>(x, emb, h16a, h16b, N);
  k_hist<<<512, 256, 0, stream>>>(dstp, hist, E);
  k_bscan<<<1, 1024, 0, stream>>>(hist, bbase, nb);
  k_scatter<<<(E + EPB - 1) / EPB, 256, 0, stream>>>(srcp, dstp, bbase, cursor,
                                                     ebuf, E, nb);
  k_csr<<<nb, 256, 0, stream>>>(ebuf, bbase, padCur, rowp, rowe, ssrc, N);
  k_wpack3<<<48, 256, 0, stream>>>(wih, ggcW, whh, Bp);

  const int nTiles = (N + 15) / 16;
  const int grid = nTiles < 2048 ? nTiles : 2048;
  _Float16* hh[2] = {h16a, h16b};
  for (int l = 0; l < 3; ++l) {
    int a = l & 1, b = 1 - a;
    k_gfu<<<grid, 256, 0, stream>>>(hh[a], hh[b], rowp, rowe, ssrc,
                                    Bp + (size_t)l * 32768,
                                    bih + (size_t)l * 192, bhh + (size_t)l * 192,
                                    batch, psum, pcnt, N, nTiles, l == 2 ? 1 : 0);
  }

  k_head<<<B, 64, 0, stream>>>(psum, pcnt, fc1W, fc1b, fc2W, fc2b, fc3W, fc3b, out);
}

// Round 13
// 224.752 us; speedup vs baseline: 1.5151x; 1.5151x over previous
//
#include <hip/hip_runtime.h>
#include <cstdint>

using h8v = __attribute__((ext_vector_type(8))) _Float16;
using h4v = __attribute__((ext_vector_type(4))) _Float16;
using f4v = __attribute__((ext_vector_type(4))) float;

__device__ __forceinline__ float sigmoidf_(float x) {
  return 1.0f / (1.0f + __expf(-x));
}
__device__ __forceinline__ float tanhf_(float x) {
  return 2.0f / (1.0f + __expf(-2.0f * x)) - 1.0f;
}

#define BN 256       // nodes per bucket
#define BCAP 4096    // LDS edge buffer cap (raw avg 2560, padded avg ~3460)
#define NBMAX 1024   // max buckets (N <= 262144)

// h16a[i][j] = emb[x[i]][j]; row N of BOTH planes = 0 (pad target row)
__global__ __launch_bounds__(256) void k_embed(const int* __restrict__ x,
                                               const float* __restrict__ emb,
                                               _Float16* __restrict__ h16a,
                                               _Float16* __restrict__ h16b, int N) {
  int idx = blockIdx.x * 256 + threadIdx.x;
  if (idx >= (N + 1) * 64) return;
  int i = idx >> 6, j = idx & 63;
  if (i < N) {
    h16a[idx] = (_Float16)emb[x[i] * 64 + j];
  } else {
    h16a[idx] = (_Float16)0.0f;
    h16b[idx] = (_Float16)0.0f;
  }
}

// bucket histogram of dst (bucket = dst>>8), LDS-aggregated
__global__ __launch_bounds__(256) void k_hist(const int* __restrict__ dst,
                                              int* __restrict__ hist, int E) {
  __shared__ int lh[NBMAX];
  for (int i = threadIdx.x; i < NBMAX; i += 256) lh[i] = 0;
  __syncthreads();
  for (int e = blockIdx.x * 256 + threadIdx.x; e < E; e += gridDim.x * 256)
    atomicAdd(&lh[dst[e] >> 8], 1);
  __syncthreads();
  for (int i = threadIdx.x; i < NBMAX; i += 256)
    if (lh[i]) atomicAdd(&hist[i], lh[i]);
}

// exclusive scan of hist -> bbase[0..nb]
__global__ __launch_bounds__(1024) void k_bscan(const int* __restrict__ hist,
                                                int* __restrict__ bbase, int nb) {
  __shared__ int sc[NBMAX];
  int t = threadIdx.x;
  int v = (t < nb) ? hist[t] : 0;
  sc[t] = v;
  __syncthreads();
  for (int off = 1; off < NBMAX; off <<= 1) {
    int xx = (t >= off) ? sc[t - off] : 0;
    __syncthreads();
    sc[t] += xx;
    __syncthreads();
  }
  if (t <= nb) bbase[t] = sc[t] - v;  // exclusive (v=0 for t==nb)
}

#define EPB 4096
// scatter edges into bucket-major chunks: ebuf[pos] = (dstLocal<<20) | src
__global__ __launch_bounds__(256) void k_scatter(const int* __restrict__ src,
                                                 const int* __restrict__ dst,
                                                 const int* __restrict__ bbase,
                                                 int* __restrict__ cursor,
                                                 unsigned* __restrict__ ebuf,
                                                 int E, int nb) {
  __shared__ int lh[NBMAX];
  __shared__ int lbase[NBMAX];
  for (int i = threadIdx.x; i < NBMAX; i += 256) lh[i] = 0;
  __syncthreads();
  const int e0 = blockIdx.x * EPB;
  const int e1 = min(e0 + EPB, E);
  for (int e = e0 + threadIdx.x; e < e1; e += 256) atomicAdd(&lh[dst[e] >> 8], 1);
  __syncthreads();
  for (int i = threadIdx.x; i < nb; i += 256) {
    int c = lh[i];
    lbase[i] = c ? (bbase[i] + atomicAdd(&cursor[i], c)) : 0;
    lh[i] = 0;
  }
  __syncthreads();
  for (int e = e0 + threadIdx.x; e < e1; e += 256) {
    int d = dst[e];
    int b = d >> 8;
    int off = atomicAdd(&lh[b], 1);
    ebuf[lbase[b] + off] = ((unsigned)(d & 255) << 20) | (unsigned)src[e];
  }
}

// per-bucket padded CSR: per-node counts, pad to multiple of 8 with src=N
// (zero row), reserve padded region via global cursor, emit rowp/rowe/ssrc.
__global__ __launch_bounds__(256) void k_csr(const unsigned* __restrict__ ebuf,
                                             const int* __restrict__ bbase,
                                             int* __restrict__ padCur,
                                             int* __restrict__ rowp,
                                             int* __restrict__ rowe,
                                             int* __restrict__ ssrc, int N) {
  __shared__ unsigned se[BCAP];
  __shared__ int ss[BCAP];
  __shared__ int cnt[BN], pex[BN], sc[BN];
  __shared__ int sbase;
  const int b = blockIdx.x;
  const int t = threadIdx.x;
  const int nbeg = b * BN;
  const int ebeg = bbase[b];
  int ne = bbase[b + 1] - ebeg;
  if (ne > BCAP) ne = BCAP;  // statistically unreachable
  for (int i = t; i < ne; i += 256) se[i] = ebuf[ebeg + i];
  cnt[t] = 0;
  __syncthreads();
  for (int i = t; i < ne; i += 256) atomicAdd(&cnt[se[i] >> 20], 1);
  __syncthreads();
  const int c = cnt[t];
  const int p = (c + 7) & ~7;  // padded size
  sc[t] = p;
  __syncthreads();
  for (int off = 1; off < BN; off <<= 1) {
    int xx = (t >= off) ? sc[t - off] : 0;
    __syncthreads();
    sc[t] += xx;
    __syncthreads();
  }
  const int pexcl = sc[t] - p;
  const int P = sc[BN - 1];  // padded bucket total
  if (t == 0) sbase = atomicAdd(padCur, P);
  pex[t] = pexcl;
  cnt[t] = 0;
  __syncthreads();
  const int n = nbeg + t;
  if (n < N) {
    rowp[n] = sbase + pexcl;
    rowe[n] = sbase + pexcl + p;
  }
  // pad entries -> zero row N
  for (int i = c; i < p; ++i) ss[pexcl + i] = N;
  // bucket-local sort by node
  for (int i = t; i < ne; i += 256) {
    unsigned e = se[i];
    int dL = e >> 20;
    int off = atomicAdd(&cnt[dL], 1);
    ss[pex[dL] + off] = (int)(e & 0xFFFFF);
  }
  __syncthreads();
  // coalesced writeout
  for (int i = t; i < P; i += 256) ssrc[sbase + i] = ss[i];
}

// All-3-layers Wp fold + fp16 MFMA-fragment pack, gate-major.
__global__ __launch_bounds__(256) void k_wpack3(const float* __restrict__ wih_all,
                                                const float* __restrict__ ggc_all,
                                                const float* __restrict__ whh_all,
                                                _Float16* __restrict__ Bp) {
  int l = blockIdx.x >> 4;  // layer
  int tid = (blockIdx.x & 15) * 256 + threadIdx.x;
  const float* wih = wih_all + (size_t)l * 192 * 64;
  const float* ggc = ggc_all + (size_t)l * 64 * 64;
  const float* whh = whh_all + (size_t)l * 192 * 64;
  int lane = tid & 63;
  int t = (tid >> 6) & 3;
  int wg = tid >> 8;
  int g = wg & 3, w = wg >> 2;
  int j = 16 * w + (lane & 15);
  int kbase = t * 32 + (lane >> 4) * 8;
  _Float16 hv[8];
#pragma unroll
  for (int i = 0; i < 8; ++i) {
    int k = kbase + i;
    float v = 0.0f;
    if (k < 64) {
      if (g < 3) {
        const float* a = wih + (size_t)(g * 64 + j) * 64;
        const float* bp = ggc + (size_t)k * 64;
        float s = 0.0f;
#pragma unroll
        for (int m = 0; m < 64; ++m) s += a[m] * bp[m];
        v = s;
      }
    } else {
      if (g != 2) {
        int row = (g == 3 ? 2 : g) * 64 + j;
        v = whh[(size_t)row * 64 + (k - 64)];
      }
    }
    hv[i] = (_Float16)v;
  }
  _Float16* o = Bp + (size_t)l * 32768 + (size_t)tid * 8;
#pragma unroll
  for (int i = 0; i < 8; ++i) o[i] = hv[i];
}

// Gather-only kernel: each 16-lane group owns one node; padded (x8) edge
// walk, 8 independent 128B row loads in flight; accumulate f32, write agg16
// row coalesced. No LDS/MFMA -> low VGPR, (256,6) = 24 waves/CU ceiling.
__global__ __launch_bounds__(256, 6) void k_agg(const _Float16* __restrict__ hin16,
                                                _Float16* __restrict__ agg16,
                                                const int* __restrict__ rowp,
                                                const int* __restrict__ rowe,
                                                const int* __restrict__ ssrc,
                                                int N) {
  const int lane = threadIdx.x & 63;
  const int w = threadIdx.x >> 6;
  const int r15 = lane & 15;
  const int node = blockIdx.x * 16 + w * 4 + (lane >> 4);
  if (node >= N) return;
  f4v a0 = {0, 0, 0, 0}, a1 = {0, 0, 0, 0}, a2 = {0, 0, 0, 0}, a3 = {0, 0, 0, 0};
  int e = rowp[node];
  const int end = rowe[node];
  for (; e < end; e += 8) {
    int s0 = ssrc[e], s1 = ssrc[e + 1], s2 = ssrc[e + 2], s3 = ssrc[e + 3];
    int s4 = ssrc[e + 4], s5 = ssrc[e + 5], s6 = ssrc[e + 6], s7 = ssrc[e + 7];
    h4v v0 = *(const h4v*)(hin16 + (size_t)s0 * 64 + 4 * r15);
    h4v v1 = *(const h4v*)(hin16 + (size_t)s1 * 64 + 4 * r15);
    h4v v2 = *(const h4v*)(hin16 + (size_t)s2 * 64 + 4 * r15);
    h4v v3 = *(const h4v*)(hin16 + (size_t)s3 * 64 + 4 * r15);
    h4v v4 = *(const h4v*)(hin16 + (size_t)s4 * 64 + 4 * r15);
    h4v v5 = *(const h4v*)(hin16 + (size_t)s5 * 64 + 4 * r15);
    h4v v6 = *(const h4v*)(hin16 + (size_t)s6 * 64 + 4 * r15);
    h4v v7 = *(const h4v*)(hin16 + (size_t)s7 * 64 + 4 * r15);
    a0 += __builtin_convertvector(v0, f4v);
    a1 += __builtin_convertvector(v1, f4v);
    a2 += __builtin_convertvector(v2, f4v);
    a3 += __builtin_convertvector(v3, f4v);
    a0 += __builtin_convertvector(v4, f4v);
    a1 += __builtin_convertvector(v5, f4v);
    a2 += __builtin_convertvector(v6, f4v);
    a3 += __builtin_convertvector(v7, f4v);
  }
  a0 += a1; a2 += a3; a0 += a2;
  *(h4v*)(agg16 + (size_t)node * 64 + 4 * r15) = __builtin_convertvector(a0, h4v);
}

#define HSTRIDE 72  // fp16 LDS row stride (64 + 8 pad)

// GRU kernel (fp16 MFMA, gate-major, in-register gates): agg A-frags direct
// from global; h staged via small LDS. last=1: fused mean-pool accumulate.
__global__ __launch_bounds__(256, 4) void k_gru(const _Float16* __restrict__ hin16,
                                                const _Float16* __restrict__ agg16,
                                                _Float16* __restrict__ hout16,
                                                const _Float16* __restrict__ Bp,
                                                const float* __restrict__ bih,
                                                const float* __restrict__ bhh,
                                                const int* __restrict__ batch,
                                                float* __restrict__ psum,
                                                float* __restrict__ pcnt,
                                                int N, int nTiles, int last) {
  __shared__ _Float16 hLds[16 * HSTRIDE];
  __shared__ _Float16 oLds[16 * HSTRIDE];
  const int lane = threadIdx.x & 63;
  const int w = threadIdx.x >> 6;
  const int r15 = lane & 15;
  const int kg8 = (lane >> 4) * 8;
  const int jj = w * 16 + r15;  // this lane's output column

  const float b_r = bih[jj] + bhh[jj];
  const float b_z = bih[64 + jj] + bhh[64 + jj];
  const float b_i = bih[128 + jj];
  const float b_h = bhh[128 + jj];

  // B fragments (zero blocks skipped): g=0,1: t=0..3 ; g=2: t=0,1 ; g=3: t=2,3
  h8v b0[4], b1[4], b2[2], b3[2];
#pragma unroll
  for (int t = 0; t < 4; ++t) {
    b0[t] = *(const h8v*)(Bp + ((size_t)((w * 4 + 0) * 4 + t) * 64 + lane) * 8);
    b1[t] = *(const h8v*)(Bp + ((size_t)((w * 4 + 1) * 4 + t) * 64 + lane) * 8);
  }
#pragma unroll
  for (int t = 0; t < 2; ++t) {
    b2[t] = *(const h8v*)(Bp + ((size_t)((w * 4 + 2) * 4 + t) * 64 + lane) * 8);
    b3[t] = *(const h8v*)(Bp + ((size_t)((w * 4 + 3) * 4 + (2 + t)) * 64 + lane) * 8);
  }

  for (int tile = blockIdx.x; tile < nTiles; tile += gridDim.x) {
    const int n0 = tile * 16;
    __syncthreads();  // prev store phase done before restaging
    // ---- stage h tile (coalesced: 16 threads cover one 128B row) ----
    {
      const int node = threadIdx.x >> 4;
      const int ci = (threadIdx.x & 15) * 4;
      const int nc = min(n0 + node, N - 1);
      *(h4v*)(hLds + node * HSTRIDE + ci) = *(const h4v*)(hin16 + (size_t)nc * 64 + ci);
    }
    __syncthreads();

    // ---- A fragments: t=0,1 direct from agg16 global, t=2,3 from hLds ----
    const int rowA = min(n0 + r15, N - 1);
    h8v ah[4];
    ah[0] = *(const h8v*)(agg16 + (size_t)rowA * 64 + kg8);
    ah[1] = *(const h8v*)(agg16 + (size_t)rowA * 64 + 32 + kg8);
    ah[2] = *(const h8v*)(hLds + r15 * HSTRIDE + kg8);
    ah[3] = *(const h8v*)(hLds + r15 * HSTRIDE + 32 + kg8);

    f4v acc0 = {0, 0, 0, 0}, acc1 = {0, 0, 0, 0}, acc2 = {0, 0, 0, 0}, acc3 = {0, 0, 0, 0};
#pragma unroll
    for (int t = 0; t < 4; ++t) {
      acc0 = __builtin_amdgcn_mfma_f32_16x16x32_f16(ah[t], b0[t], acc0, 0, 0, 0);
      acc1 = __builtin_amdgcn_mfma_f32_16x16x32_f16(ah[t], b1[t], acc1, 0, 0, 0);
    }
    acc2 = __builtin_amdgcn_mfma_f32_16x16x32_f16(ah[0], b2[0], acc2, 0, 0, 0);
    acc2 = __builtin_amdgcn_mfma_f32_16x16x32_f16(ah[1], b2[1], acc2, 0, 0, 0);
    acc3 = __builtin_amdgcn_mfma_f32_16x16x32_f16(ah[2], b3[0], acc3, 0, 0, 0);
    acc3 = __builtin_amdgcn_mfma_f32_16x16x32_f16(ah[3], b3[1], acc3, 0, 0, 0);

    // ---- in-register gates: C row = (lane>>4)*4 + q, col = jj [m89] ----
    const int rb = (lane >> 4) * 4;
#pragma unroll
    for (int q = 0; q < 4; ++q) {
      int row = rb + q;
      float hold = (float)hLds[row * HSTRIDE + jj];
      float r = sigmoidf_(acc0[q] + b_r);
      float z = sigmoidf_(acc1[q] + b_z);
      float nv = tanhf_(acc2[q] + b_i + r * (acc3[q] + b_h));
      float o = (1.0f - z) * nv + z * hold;
      oLds[row * HSTRIDE + jj] = (_Float16)fmaxf(o, 0.0f);
    }
    __syncthreads();

    // ---- store phase ----
    if (!last) {
      const int node = threadIdx.x >> 4;
      const int ci = (threadIdx.x & 15) * 4;
      const int n = n0 + node;
      if (n < N) {
        h4v o = *(const h4v*)(oLds + node * HSTRIDE + ci);
        *(h4v*)(hout16 + (size_t)n * 64 + ci) = o;
      }
    } else {
      // fused segment-mean accumulate (batch sorted): wave 0 walks the tile
      if (threadIdx.x < 64) {
        int curb = batch[n0];
        float acc = 0.0f, ca = 0.0f;
#pragma unroll 1
        for (int i = 0; i < 16; ++i) {
          int n = n0 + i;
          if (n >= N) break;
          int b = batch[n];
          if (b != curb) {
            atomicAdd(&psum[curb * 64 + lane], acc);
            if (lane == 0) atomicAdd(&pcnt[curb], ca);
            acc = 0.0f; ca = 0.0f; curb = b;
          }
          acc += (float)oLds[i * HSTRIDE + lane];
          ca += 1.0f;
        }
        atomicAdd(&psum[curb * 64 + lane], acc);
        if (lane == 0) atomicAdd(&pcnt[curb], ca);
      }
    }
  }
}

// MLP head: 64 -> 32 -> 16 -> 1, one 64-thread block per batch element
__global__ __launch_bounds__(64) void k_head(const float* __restrict__ psum,
                                             const float* __restrict__ pcnt,
                                             const float* __restrict__ fc1W,
                                             const float* __restrict__ fc1b,
                                             const float* __restrict__ fc2W,
                                             const float* __restrict__ fc2b,
                                             const float* __restrict__ fc3W,
                                             const float* __restrict__ fc3b,
                                             float* __restrict__ out) {
  int b = blockIdx.x;
  int j = threadIdx.x;
  float c = fmaxf(pcnt[b], 1.0f);
  float p = psum[b * 64 + j] / c;
  int j1 = j & 31;
  float y1 = fc1b[j1];
#pragma unroll
  for (int k = 0; k < 64; ++k) y1 += fc1W[j1 * 64 + k] * __shfl(p, k, 64);
  y1 = fmaxf(y1, 0.0f);
  int j2 = j & 15;
  float y2 = fc2b[j2];
#pragma unroll
  for (int k = 0; k < 32; ++k) y2 += fc2W[j2 * 32 + k] * __shfl(y1, k, 64);
  y2 = fmaxf(y2, 0.0f);
  float y = 0.0f;
#pragma unroll
  for (int k = 0; k < 16; ++k) y += fc3W[k] * __shfl(y2, k, 64);
  if (j == 0) out[b] = y + fc3b[0];
}

extern "C" void kernel_launch(void* const* d_in, const int* in_sizes, int n_in,
                              void* d_out, int out_size, void* d_ws, size_t ws_size,
                              hipStream_t stream) {
  const int N = in_sizes[0];
  const int E = in_sizes[1] / 2;
  const int B = out_size;

  const int* x = (const int*)d_in[0];
  const int* eidx = (const int*)d_in[1];
  const int* batch = (const int*)d_in[3];
  const float* emb = (const float*)d_in[4];
  const float* ggcW = (const float*)d_in[7];
  const float* wih = (const float*)d_in[8];
  const float* whh = (const float*)d_in[9];
  const float* bih = (const float*)d_in[10];
  const float* bhh = (const float*)d_in[11];
  const float* fc1W = (const float*)d_in[12];
  const float* fc1b = (const float*)d_in[13];
  const float* fc2W = (const float*)d_in[14];
  const float* fc2b = (const float*)d_in[15];
  const float* fc3W = (const float*)d_in[16];
  const float* fc3b = (const float*)d_in[17];
  float* out = (float*)d_out;

  const int* srcp = eidx;
  const int* dstp = eidx + E;
  const int nb = (N + BN - 1) / BN;  // buckets

  char* ws = (char*)d_ws;
  size_t off = 0;
  auto alloc = [&](size_t bytes) -> void* {
    void* p = ws + off;
    off = (off + bytes + 255) & ~(size_t)255;
    return p;
  };
  _Float16* h16a = (_Float16*)alloc((size_t)(N + 1) * 64 * 2);
  _Float16* h16b = (_Float16*)alloc((size_t)(N + 1) * 64 * 2);
  _Float16* agg16 = (_Float16*)alloc((size_t)N * 64 * 2);
  int* rowp = (int*)alloc((size_t)(N + 1) * 4);
  int* rowe = (int*)alloc((size_t)(N + 1) * 4);
  int* ssrc = (int*)alloc(((size_t)E + 8 * (size_t)N) * 4);  // padded
  unsigned* ebuf = (unsigned*)alloc((size_t)E * 4);
  int* bbase = (int*)alloc((size_t)(NBMAX + 1) * 4);
  // contiguous zero region: hist | cursor | padCur | pool -> ONE memset
  size_t zbeg = off;
  int* hist = (int*)alloc((size_t)NBMAX * 4);
  int* cursor = (int*)alloc((size_t)NBMAX * 4);
  int* padCur = (int*)alloc(256);
  float* pool = (float*)alloc((size_t)(B * 64 + B) * 4);
  size_t zend = off;
  float* psum = pool;
  float* pcnt = pool + (size_t)B * 64;
  _Float16* Bp = (_Float16*)alloc((size_t)3 * 32768 * 2);

  // --- bucketed padded-CSR build (coalesced writes) + embed + weight pack ---
  hipMemsetAsync(ws + zbeg, 0, zend - zbeg, stream);
  k_embed<<<((N + 1) * 64 + 255) / 256, 256, 0, stream>>>(x, emb, h16a, h16b, N);
  k_hist<<<512, 256, 0, stream>>>(dstp, hist, E);
  k_bscan<<<1, 1024, 0, stream>>>(hist, bbase, nb);
  k_scatter<<<(E + EPB - 1) / EPB, 256, 0, stream>>>(srcp, dstp, bbase, cursor,
                                                     ebuf, E, nb);
  k_csr<<<nb, 256, 0, stream>>>(ebuf, bbase, padCur, rowp, rowe, ssrc, N);
  k_wpack3<<<48, 256, 0, stream>>>(wih, ggcW, whh, Bp);

  const int nTiles = (N + 15) / 16;
  const int grid = nTiles < 2048 ? nTiles : 2048;
  _Float16* hh[2] = {h16a, h16b};
  for (int l = 0; l < 3; ++l) {
    int a = l & 1, b = 1 - a;
    k_agg<<<nTiles, 256, 0, stream>>>(hh[a], agg16, rowp, rowe, ssrc, N);
    k_gru<<<grid, 256, 0, stream>>>(hh[a], agg16, hh[b], Bp + (size_t)l * 32768,
                                    bih + (size_t)l * 192, bhh + (size_t)l * 192,
                                    batch, psum, pcnt, N, nTiles, l == 2 ? 1 : 0);
  }

  k_head<<<B, 64, 0, stream>>>(psum, pcnt, fc1W, fc1b, fc2W, fc2b, fc3W, fc3b, out);
}

// Round 14
// 208.946 us; speedup vs baseline: 1.6297x; 1.0756x over previous
//
#include <hip/hip_runtime.h>
#include <cstdint>

using h8v = __attribute__((ext_vector_type(8))) _Float16;
using h4v = __attribute__((ext_vector_type(4))) _Float16;
using f4v = __attribute__((ext_vector_type(4))) float;

__device__ __forceinline__ float sigmoidf_(float x) {
  return 1.0f / (1.0f + __expf(-x));
}
__device__ __forceinline__ float tanhf_(float x) {
  return 2.0f / (1.0f + __expf(-2.0f * x)) - 1.0f;
}

#define BN 256       // nodes per bucket
#define BCAP 4096    // LDS edge buffer cap (raw avg 2560, padded avg ~3460)
#define NBMAX 1024   // max buckets (N <= 262144)

// h16a[i][j] = emb[x[i]][j]; row N of BOTH planes = 0 (pad target row).
// Also zeroes the scratch region (hist|cursor|padCur|pool) -- replaces 4
// hipMemsetAsync dispatches; stream order makes it visible to k_hist etc.
__global__ __launch_bounds__(256) void k_embed(const int* __restrict__ x,
                                               const float* __restrict__ emb,
                                               _Float16* __restrict__ h16a,
                                               _Float16* __restrict__ h16b,
                                               int* __restrict__ zbuf, int zwords,
                                               int N) {
  int idx = blockIdx.x * 256 + threadIdx.x;
  if (idx < zwords) zbuf[idx] = 0;
  if (idx >= (N + 1) * 64) return;
  int i = idx >> 6, j = idx & 63;
  if (i < N) {
    h16a[idx] = (_Float16)emb[x[i] * 64 + j];
  } else {
    h16a[idx] = (_Float16)0.0f;
    h16b[idx] = (_Float16)0.0f;
  }
}

// bucket histogram of dst (bucket = dst>>8), LDS-aggregated
__global__ __launch_bounds__(256) void k_hist(const int* __restrict__ dst,
                                              int* __restrict__ hist, int E) {
  __shared__ int lh[NBMAX];
  for (int i = threadIdx.x; i < NBMAX; i += 256) lh[i] = 0;
  __syncthreads();
  for (int e = blockIdx.x * 256 + threadIdx.x; e < E; e += gridDim.x * 256)
    atomicAdd(&lh[dst[e] >> 8], 1);
  __syncthreads();
  for (int i = threadIdx.x; i < NBMAX; i += 256)
    if (lh[i]) atomicAdd(&hist[i], lh[i]);
}

// exclusive scan of hist -> bbase[0..nb]
__global__ __launch_bounds__(1024) void k_bscan(const int* __restrict__ hist,
                                                int* __restrict__ bbase, int nb) {
  __shared__ int sc[NBMAX];
  int t = threadIdx.x;
  int v = (t < nb) ? hist[t] : 0;
  sc[t] = v;
  __syncthreads();
  for (int off = 1; off < NBMAX; off <<= 1) {
    int xx = (t >= off) ? sc[t - off] : 0;
    __syncthreads();
    sc[t] += xx;
    __syncthreads();
  }
  if (t <= nb) bbase[t] = sc[t] - v;  // exclusive (v=0 for t==nb)
}

#define EPB 4096
// scatter edges into bucket-major chunks: ebuf[pos] = (dstLocal<<20) | src
__global__ __launch_bounds__(256) void k_scatter(const int* __restrict__ src,
                                                 const int* __restrict__ dst,
                                                 const int* __restrict__ bbase,
                                                 int* __restrict__ cursor,
                                                 unsigned* __restrict__ ebuf,
                                                 int E, int nb) {
  __shared__ int lh[NBMAX];
  __shared__ int lbase[NBMAX];
  for (int i = threadIdx.x; i < NBMAX; i += 256) lh[i] = 0;
  __syncthreads();
  const int e0 = blockIdx.x * EPB;
  const int e1 = min(e0 + EPB, E);
  for (int e = e0 + threadIdx.x; e < e1; e += 256) atomicAdd(&lh[dst[e] >> 8], 1);
  __syncthreads();
  for (int i = threadIdx.x; i < nb; i += 256) {
    int c = lh[i];
    lbase[i] = c ? (bbase[i] + atomicAdd(&cursor[i], c)) : 0;
    lh[i] = 0;
  }
  __syncthreads();
  for (int e = e0 + threadIdx.x; e < e1; e += 256) {
    int d = dst[e];
    int b = d >> 8;
    int off = atomicAdd(&lh[b], 1);
    ebuf[lbase[b] + off] = ((unsigned)(d & 255) << 20) | (unsigned)src[e];
  }
}

// per-bucket padded CSR: per-node counts, pad to multiple of 8 with src=N
// (zero row), reserve padded region via global cursor, emit rowp/rowe/ssrc.
__global__ __launch_bounds__(256) void k_csr(const unsigned* __restrict__ ebuf,
                                             const int* __restrict__ bbase,
                                             int* __restrict__ padCur,
                                             int* __restrict__ rowp,
                                             int* __restrict__ rowe,
                                             int* __restrict__ ssrc, int N) {
  __shared__ unsigned se[BCAP];
  __shared__ int ss[BCAP];
  __shared__ int cnt[BN], pex[BN], sc[BN];
  __shared__ int sbase;
  const int b = blockIdx.x;
  const int t = threadIdx.x;
  const int nbeg = b * BN;
  const int ebeg = bbase[b];
  int ne = bbase[b + 1] - ebeg;
  if (ne > BCAP) ne = BCAP;  // statistically unreachable
  for (int i = t; i < ne; i += 256) se[i] = ebuf[ebeg + i];
  cnt[t] = 0;
  __syncthreads();
  for (int i = t; i < ne; i += 256) atomicAdd(&cnt[se[i] >> 20], 1);
  __syncthreads();
  const int c = cnt[t];
  const int p = (c + 7) & ~7;  // padded size
  sc[t] = p;
  __syncthreads();
  for (int off = 1; off < BN; off <<= 1) {
    int xx = (t >= off) ? sc[t - off] : 0;
    __syncthreads();
    sc[t] += xx;
    __syncthreads();
  }
  const int pexcl = sc[t] - p;
  const int P = sc[BN - 1];  // padded bucket total
  if (t == 0) sbase = atomicAdd(padCur, P);
  pex[t] = pexcl;
  cnt[t] = 0;
  __syncthreads();
  const int n = nbeg + t;
  if (n < N) {
    rowp[n] = sbase + pexcl;
    rowe[n] = sbase + pexcl + p;
  }
  // pad entries -> zero row N
  for (int i = c; i < p; ++i) ss[pexcl + i] = N;
  // bucket-local sort by node
  for (int i = t; i < ne; i += 256) {
    unsigned e = se[i];
    int dL = e >> 20;
    int off = atomicAdd(&cnt[dL], 1);
    ss[pex[dL] + off] = (int)(e & 0xFFFFF);
  }
  __syncthreads();
  // coalesced writeout
  for (int i = t; i < P; i += 256) ssrc[sbase + i] = ss[i];
}

// All-3-layers Wp fold + fp16 MFMA-fragment pack, gate-major.
// Per layer: idx = (((w*4+g)*4+t)*64+lane)*8+i holds
// B[32t + 8*(lane>>4) + i][gate g, col 16w + (lane&15)],
// B[k][g,j] = (k<64) ? Wp[64g'+j][k] : whh[64g''+j][k-64]
//   g=0: r (Wp j ; whh j),  g=1: z (Wp 64+j ; whh 64+j),
//   g=2: inn (Wp 128+j ; 0),  g=3: hn (0 ; whh 128+j)
// Wp[r][k] = sum_m wih[r][m] * ggc[k][m].
__global__ __launch_bounds__(256) void k_wpack3(const float* __restrict__ wih_all,
                                                const float* __restrict__ ggc_all,
                                                const float* __restrict__ whh_all,
                                                _Float16* __restrict__ Bp) {
  int l = blockIdx.x >> 4;  // layer
  int tid = (blockIdx.x & 15) * 256 + threadIdx.x;
  const float* wih = wih_all + (size_t)l * 192 * 64;
  const float* ggc = ggc_all + (size_t)l * 64 * 64;
  const float* whh = whh_all + (size_t)l * 192 * 64;
  int lane = tid & 63;
  int t = (tid >> 6) & 3;
  int wg = tid >> 8;
  int g = wg & 3, w = wg >> 2;
  int j = 16 * w + (lane & 15);
  int kbase = t * 32 + (lane >> 4) * 8;
  _Float16 hv[8];
#pragma unroll
  for (int i = 0; i < 8; ++i) {
    int k = kbase + i;
    float v = 0.0f;
    if (k < 64) {
      if (g < 3) {
        const float* a = wih + (size_t)(g * 64 + j) * 64;
        const float* bp = ggc + (size_t)k * 64;
        float s = 0.0f;
#pragma unroll
        for (int m = 0; m < 64; ++m) s += a[m] * bp[m];
        v = s;
      }
    } else {
      if (g != 2) {
        int row = (g == 3 ? 2 : g) * 64 + j;
        v = whh[(size_t)row * 64 + (k - 64)];
      }
    }
    hv[i] = (_Float16)v;
  }
  _Float16* o = Bp + (size_t)l * 32768 + (size_t)tid * 8;
#pragma unroll
  for (int i = 0; i < 8; ++i) o[i] = hv[i];
}

__device__ __forceinline__ h8v f32lds_to_h8(const float* __restrict__ p) {
  f4v x0 = *(const f4v*)p;
  f4v x1 = *(const f4v*)(p + 4);
  h8v r;
#pragma unroll
  for (int i = 0; i < 4; ++i) {
    r[i] = (_Float16)x0[i];
    r[4 + i] = (_Float16)x1[i];
  }
  return r;
}

#define FSTRIDE 68  // f32 LDS row stride (64 + 4 pad)
#define HSTRIDE 72  // fp16 LDS row stride (64 + 8 pad)

// Fused CSR-gather + GRU (fp16 MFMA, gate-major, in-register gates),
// fp16-only h plane, coalesced stores via LDS exchange.
// Gather: padded edge lists (multiple of 8, pads -> zero row N), single
// uniform 8-deep loop with no tail. (256,4): proven config -- tighter
// bounds make the allocator restructure (r6: 40 VGPR sink; r12: 32+spill).
// last=1: fused mean-pool accumulate instead of h stores.
__global__ __launch_bounds__(256, 4) void k_gfu(const _Float16* __restrict__ hin16,
                                                _Float16* __restrict__ hout16,
                                                const int* __restrict__ rowp,
                                                const int* __restrict__ rowe,
                                                const int* __restrict__ ssrc,
                                                const _Float16* __restrict__ Bp,
                                                const float* __restrict__ bih,
                                                const float* __restrict__ bhh,
                                                const int* __restrict__ batch,
                                                float* __restrict__ psum,
                                                float* __restrict__ pcnt,
                                                int N, int nTiles, int last) {
  __shared__ float aggLds[16 * FSTRIDE];
  __shared__ _Float16 hLds[16 * HSTRIDE];
  __shared__ _Float16 oLds[16 * HSTRIDE];
  const int lane = threadIdx.x & 63;
  const int w = threadIdx.x >> 6;
  const int r15 = lane & 15;
  const int kg8 = (lane >> 4) * 8;
  const int jj = w * 16 + r15;  // this lane's output column

  const float b_r = bih[jj] + bhh[jj];
  const float b_z = bih[64 + jj] + bhh[64 + jj];
  const float b_i = bih[128 + jj];
  const float b_h = bhh[128 + jj];

  // B fragments (zero blocks skipped): g=0,1: t=0..3 ; g=2: t=0,1 ; g=3: t=2,3
  h8v b0[4], b1[4], b2[2], b3[2];
#pragma unroll
  for (int t = 0; t < 4; ++t) {
    b0[t] = *(const h8v*)(Bp + ((size_t)((w * 4 + 0) * 4 + t) * 64 + lane) * 8);
    b1[t] = *(const h8v*)(Bp + ((size_t)((w * 4 + 1) * 4 + t) * 64 + lane) * 8);
  }
#pragma unroll
  for (int t = 0; t < 2; ++t) {
    b2[t] = *(const h8v*)(Bp + ((size_t)((w * 4 + 2) * 4 + t) * 64 + lane) * 8);
    b3[t] = *(const h8v*)(Bp + ((size_t)((w * 4 + 3) * 4 + (2 + t)) * 64 + lane) * 8);
  }

  for (int tile = blockIdx.x; tile < nTiles; tile += gridDim.x) {
    const int n0 = tile * 16;
    __syncthreads();  // prev store phase done before restaging
    // ---- gather + fp16 h staging (each 16-lane group owns a node) ----
    {
      const int g = lane >> 4;
      const int node = 4 * w + g;
      const int n = n0 + node;
      const int nc = min(n, N - 1);
      h4v hv = *(const h4v*)(hin16 + (size_t)nc * 64 + 4 * r15);
      f4v a0 = {0, 0, 0, 0}, a1 = {0, 0, 0, 0}, a2 = {0, 0, 0, 0}, a3 = {0, 0, 0, 0};
      if (n < N) {
        int e = rowp[n];
        const int end = rowe[n];
        // uniform 8-deep loop, no tail (padded lists; pads hit zero row)
        for (; e < end; e += 8) {
          int s0 = ssrc[e], s1 = ssrc[e + 1], s2 = ssrc[e + 2], s3 = ssrc[e + 3];
          int s4 = ssrc[e + 4], s5 = ssrc[e + 5], s6 = ssrc[e + 6], s7 = ssrc[e + 7];
          h4v v0 = *(const h4v*)(hin16 + (size_t)s0 * 64 + 4 * r15);
          h4v v1 = *(const h4v*)(hin16 + (size_t)s1 * 64 + 4 * r15);
          h4v v2 = *(const h4v*)(hin16 + (size_t)s2 * 64 + 4 * r15);
          h4v v3 = *(const h4v*)(hin16 + (size_t)s3 * 64 + 4 * r15);
          h4v v4 = *(const h4v*)(hin16 + (size_t)s4 * 64 + 4 * r15);
          h4v v5 = *(const h4v*)(hin16 + (size_t)s5 * 64 + 4 * r15);
          h4v v6 = *(const h4v*)(hin16 + (size_t)s6 * 64 + 4 * r15);
          h4v v7 = *(const h4v*)(hin16 + (size_t)s7 * 64 + 4 * r15);
          a0 += __builtin_convertvector(v0, f4v);
          a1 += __builtin_convertvector(v1, f4v);
          a2 += __builtin_convertvector(v2, f4v);
          a3 += __builtin_convertvector(v3, f4v);
          a0 += __builtin_convertvector(v4, f4v);
          a1 += __builtin_convertvector(v5, f4v);
          a2 += __builtin_convertvector(v6, f4v);
          a3 += __builtin_convertvector(v7, f4v);
        }
      }
      a0 += a1; a2 += a3; a0 += a2;
      *(f4v*)(aggLds + node * FSTRIDE + 4 * r15) = a0;
      *(h4v*)(hLds + node * HSTRIDE + 4 * r15) = hv;
    }
    __syncthreads();

    // ---- A fragments: t=0,1 from agg (f32->fp16), t=2,3 direct fp16 ----
    h8v ah[4];
#pragma unroll
    for (int t = 0; t < 2; ++t)
      ah[t] = f32lds_to_h8(aggLds + r15 * FSTRIDE + t * 32 + kg8);
#pragma unroll
    for (int t = 0; t < 2; ++t)
      ah[2 + t] = *(const h8v*)(hLds + r15 * HSTRIDE + t * 32 + kg8);

    f4v acc0 = {0, 0, 0, 0}, acc1 = {0, 0, 0, 0}, acc2 = {0, 0, 0, 0}, acc3 = {0, 0, 0, 0};
#pragma unroll
    for (int t = 0; t < 4; ++t) {
      acc0 = __builtin_amdgcn_mfma_f32_16x16x32_f16(ah[t], b0[t], acc0, 0, 0, 0);
      acc1 = __builtin_amdgcn_mfma_f32_16x16x32_f16(ah[t], b1[t], acc1, 0, 0, 0);
    }
    acc2 = __builtin_amdgcn_mfma_f32_16x16x32_f16(ah[0], b2[0], acc2, 0, 0, 0);
    acc2 = __builtin_amdgcn_mfma_f32_16x16x32_f16(ah[1], b2[1], acc2, 0, 0, 0);
    acc3 = __builtin_amdgcn_mfma_f32_16x16x32_f16(ah[2], b3[0], acc3, 0, 0, 0);
    acc3 = __builtin_amdgcn_mfma_f32_16x16x32_f16(ah[3], b3[1], acc3, 0, 0, 0);

    // ---- in-register gates: C row = (lane>>4)*4 + q, col = jj [m89] ----
    const int rb = (lane >> 4) * 4;
#pragma unroll
    for (int q = 0; q < 4; ++q) {
      int row = rb + q;
      float hold = (float)hLds[row * HSTRIDE + jj];
      float r = sigmoidf_(acc0[q] + b_r);
      float z = sigmoidf_(acc1[q] + b_z);
      float nv = tanhf_(acc2[q] + b_i + r * (acc3[q] + b_h));
      float o = (1.0f - z) * nv + z * hold;
      oLds[row * HSTRIDE + jj] = (_Float16)fmaxf(o, 0.0f);
    }
    __syncthreads();

    // ---- store phase ----
    if (!last) {
      // coalesced full-row stores: 16 threads cover one 128B fp16 row
      const int node = threadIdx.x >> 4;
      const int ci = (threadIdx.x & 15) * 4;
      const int n = n0 + node;
      if (n < N) {
        h4v o = *(const h4v*)(oLds + node * HSTRIDE + ci);
        *(h4v*)(hout16 + (size_t)n * 64 + ci) = o;
      }
    } else {
      // fused segment-mean accumulate (batch sorted): wave 0 walks the tile
      if (threadIdx.x < 64) {
        int curb = batch[n0];
        float acc = 0.0f, ca = 0.0f;
#pragma unroll 1
        for (int i = 0; i < 16; ++i) {
          int n = n0 + i;
          if (n >= N) break;
          int b = batch[n];
          if (b != curb) {
            atomicAdd(&psum[curb * 64 + lane], acc);
            if (lane == 0) atomicAdd(&pcnt[curb], ca);
            acc = 0.0f; ca = 0.0f; curb = b;
          }
          acc += (float)oLds[i * HSTRIDE + lane];
          ca += 1.0f;
        }
        atomicAdd(&psum[curb * 64 + lane], acc);
        if (lane == 0) atomicAdd(&pcnt[curb], ca);
      }
    }
  }
}

// MLP head: 64 -> 32 -> 16 -> 1, one 64-thread block per batch element
__global__ __launch_bounds__(64) void k_head(const float* __restrict__ psum,
                                             const float* __restrict__ pcnt,
                                             const float* __restrict__ fc1W,
                                             const float* __restrict__ fc1b,
                                             const float* __restrict__ fc2W,
                                             const float* __restrict__ fc2b,
                                             const float* __restrict__ fc3W,
                                             const float* __restrict__ fc3b,
                                             float* __restrict__ out) {
  int b = blockIdx.x;
  int j = threadIdx.x;
  float c = fmaxf(pcnt[b], 1.0f);
  float p = psum[b * 64 + j] / c;
  int j1 = j & 31;
  float y1 = fc1b[j1];
#pragma unroll
  for (int k = 0; k < 64; ++k) y1 += fc1W[j1 * 64 + k] * __shfl(p, k, 64);
  y1 = fmaxf(y1, 0.0f);
  int j2 = j & 15;
  float y2 = fc2b[j2];
#pragma unroll
  for (int k = 0; k < 32; ++k) y2 += fc2W[j2 * 32 + k] * __shfl(y1, k, 64);
  y2 = fmaxf(y2, 0.0f);
  float y = 0.0f;
#pragma unroll
  for (int k = 0; k < 16; ++k) y += fc3W[k] * __shfl(y2, k, 64);
  if (j == 0) out[b] = y + fc3b[0];
}

extern "C" void kernel_launch(void* const* d_in, const int* in_sizes, int n_in,
                              void* d_out, int out_size, void* d_ws, size_t ws_size,
                              hipStream_t stream) {
  const int N = in_sizes[0];
  const int E = in_sizes[1] / 2;
  const int B = out_size;

  const int* x = (const int*)d_in[0];
  const int* eidx = (const int*)d_in[1];
  const int* batch = (const int*)d_in[3];
  const float* emb = (const float*)d_in[4];
  const float* ggcW = (const float*)d_in[7];
  const float* wih = (const float*)d_in[8];
  const float* whh = (const float*)d_in[9];
  const float* bih = (const float*)d_in[10];
  const float* bhh = (const float*)d_in[11];
  const float* fc1W = (const float*)d_in[12];
  const float* fc1b = (const float*)d_in[13];
  const float* fc2W = (const float*)d_in[14];
  const float* fc2b = (const float*)d_in[15];
  const float* fc3W = (const float*)d_in[16];
  const float* fc3b = (const float*)d_in[17];
  float* out = (float*)d_out;

  const int* srcp = eidx;
  const int* dstp = eidx + E;
  const int nb = (N + BN - 1) / BN;  // buckets

  char* ws = (char*)d_ws;
  size_t off = 0;
  auto alloc = [&](size_t bytes) -> void* {
    void* p = ws + off;
    off = (off + bytes + 255) & ~(size_t)255;
    return p;
  };
  _Float16* h16a = (_Float16*)alloc((size_t)(N + 1) * 64 * 2);
  _Float16* h16b = (_Float16*)alloc((size_t)(N + 1) * 64 * 2);
  int* rowp = (int*)alloc((size_t)(N + 1) * 4);
  int* rowe = (int*)alloc((size_t)(N + 1) * 4);
  int* ssrc = (int*)alloc(((size_t)E + 8 * (size_t)N) * 4);  // padded
  unsigned* ebuf = (unsigned*)alloc((size_t)E * 4);
  int* bbase = (int*)alloc((size_t)(NBMAX + 1) * 4);
  // contiguous zero region: hist | cursor | padCur | pool -> zeroed by k_embed
  size_t zbeg = off;
  int* hist = (int*)alloc((size_t)NBMAX * 4);
  int* cursor = (int*)alloc((size_t)NBMAX * 4);
  int* padCur = (int*)alloc(256);
  float* pool = (float*)alloc((size_t)(B * 64 + B) * 4);
  size_t zend = off;
  float* psum = pool;
  float* pcnt = pool + (size_t)B * 64;
  _Float16* Bp = (_Float16*)alloc((size_t)3 * 32768 * 2);
  const int zwords = (int)((zend - zbeg) / 4);

  // --- preamble: embed (+scratch zero) -> bucketed padded-CSR -> weight pack
  k_embed<<<((N + 1) * 64 + 255) / 256, 256, 0, stream>>>(
      x, emb, h16a, h16b, (int*)(ws + zbeg), zwords, N);
  k_hist<<<512, 256, 0, stream>>>(dstp, hist, E);
  k_bscan<<<1, 1024, 0, stream>>>(hist, bbase, nb);
  k_scatter<<<(E + EPB - 1) / EPB, 256, 0, stream>>>(srcp, dstp, bbase, cursor,
                                                     ebuf, E, nb);
  k_csr<<<nb, 256, 0, stream>>>(ebuf, bbase, padCur, rowp, rowe, ssrc, N);
  k_wpack3<<<48, 256, 0, stream>>>(wih, ggcW, whh, Bp);

  const int nTiles = (N + 15) / 16;
  const int grid = nTiles < 2048 ? nTiles : 2048;
  _Float16* hh[2] = {h16a, h16b};
  for (int l = 0; l < 3; ++l) {
    int a = l & 1, b = 1 - a;
    k_gfu<<<grid, 256, 0, stream>>>(hh[a], hh[b], rowp, rowe, ssrc,
                                    Bp + (size_t)l * 32768,
                                    bih + (size_t)l * 192, bhh + (size_t)l * 192,
                                    batch, psum, pcnt, N, nTiles, l == 2 ? 1 : 0);
  }

  k_head<<<B, 64, 0, stream>>>(psum, pcnt, fc1W, fc1b, fc2W, fc2b, fc3W, fc3b, out);
}

// Round 15
// 203.242 us; speedup vs baseline: 1.6754x; 1.0281x over previous
//
#include <hip/hip_runtime.h>
#include <cstdint>

using h8v = __attribute__((ext_vector_type(8))) _Float16;
using h4v = __attribute__((ext_vector_type(4))) _Float16;
using f4v = __attribute__((ext_vector_type(4))) float;

__device__ __forceinline__ float sigmoidf_(float x) {
  return 1.0f / (1.0f + __expf(-x));
}
__device__ __forceinline__ float tanhf_(float x) {
  return 2.0f / (1.0f + __expf(-2.0f * x)) - 1.0f;
}

#define BN 256       // nodes per bucket
#define BCAP 4096    // LDS edge buffer cap (raw avg 2560, padded avg ~3460)
#define NBMAX 1024   // max buckets (N <= 262144)

// h16a[i][j] = emb[x[i]][j]; row N of BOTH planes = 0 (pad target row).
// Also zeroes the scratch region (replaces memsets) AND blocks <512 do the
// bucket histogram of dst (bucket = dst>>8) with LDS aggregation.
__global__ __launch_bounds__(256) void k_embed(const int* __restrict__ x,
                                               const float* __restrict__ emb,
                                               _Float16* __restrict__ h16a,
                                               _Float16* __restrict__ h16b,
                                               int* __restrict__ zbuf, int zwords,
                                               const int* __restrict__ dst,
                                               int* __restrict__ hist,
                                               int N, int E) {
  __shared__ int lh[NBMAX];
  int idx = blockIdx.x * 256 + threadIdx.x;
  if (idx < zwords) zbuf[idx] = 0;
  if (idx < (N + 1) * 64) {
    int i = idx >> 6, j = idx & 63;
    if (i < N) {
      h16a[idx] = (_Float16)emb[x[i] * 64 + j];
    } else {
      h16a[idx] = (_Float16)0.0f;
      h16b[idx] = (_Float16)0.0f;
    }
  }
  if (blockIdx.x < 512) {
    for (int i = threadIdx.x; i < NBMAX; i += 256) lh[i] = 0;
    __syncthreads();
    for (int e = blockIdx.x * 256 + threadIdx.x; e < E; e += 512 * 256)
      atomicAdd(&lh[dst[e] >> 8], 1);
    __syncthreads();
    for (int i = threadIdx.x; i < NBMAX; i += 256)
      if (lh[i]) atomicAdd(&hist[i], lh[i]);
  }
}

// exclusive scan of hist -> bbase[0..nb]
__global__ __launch_bounds__(1024) void k_bscan(const int* __restrict__ hist,
                                                int* __restrict__ bbase, int nb) {
  __shared__ int sc[NBMAX];
  int t = threadIdx.x;
  int v = (t < nb) ? hist[t] : 0;
  sc[t] = v;
  __syncthreads();
  for (int off = 1; off < NBMAX; off <<= 1) {
    int xx = (t >= off) ? sc[t - off] : 0;
    __syncthreads();
    sc[t] += xx;
    __syncthreads();
  }
  if (t <= nb) bbase[t] = sc[t] - v;  // exclusive (v=0 for t==nb)
}

#define EPB 4096
// scatter edges into bucket-major chunks: ebuf[pos] = (dstLocal<<20) | src
__global__ __launch_bounds__(256) void k_scatter(const int* __restrict__ src,
                                                 const int* __restrict__ dst,
                                                 const int* __restrict__ bbase,
                                                 int* __restrict__ cursor,
                                                 unsigned* __restrict__ ebuf,
                                                 int E, int nb) {
  __shared__ int lh[NBMAX];
  __shared__ int lbase[NBMAX];
  for (int i = threadIdx.x; i < NBMAX; i += 256) lh[i] = 0;
  __syncthreads();
  const int e0 = blockIdx.x * EPB;
  const int e1 = min(e0 + EPB, E);
  for (int e = e0 + threadIdx.x; e < e1; e += 256) atomicAdd(&lh[dst[e] >> 8], 1);
  __syncthreads();
  for (int i = threadIdx.x; i < nb; i += 256) {
    int c = lh[i];
    lbase[i] = c ? (bbase[i] + atomicAdd(&cursor[i], c)) : 0;
    lh[i] = 0;
  }
  __syncthreads();
  for (int e = e0 + threadIdx.x; e < e1; e += 256) {
    int d = dst[e];
    int b = d >> 8;
    int off = atomicAdd(&lh[b], 1);
    ebuf[lbase[b] + off] = ((unsigned)(d & 255) << 20) | (unsigned)src[e];
  }
}

// per-bucket padded CSR: per-node counts, pad to multiple of 8 with src=N
// (zero row), reserve padded region via global cursor, emit rowp/rowe/ssrc.
__global__ __launch_bounds__(256) void k_csr(const unsigned* __restrict__ ebuf,
                                             const int* __restrict__ bbase,
                                             int* __restrict__ padCur,
                                             int* __restrict__ rowp,
                                             int* __restrict__ rowe,
                                             int* __restrict__ ssrc, int N) {
  __shared__ unsigned se[BCAP];
  __shared__ int ss[BCAP];
  __shared__ int cnt[BN], pex[BN], sc[BN];
  __shared__ int sbase;
  const int b = blockIdx.x;
  const int t = threadIdx.x;
  const int nbeg = b * BN;
  const int ebeg = bbase[b];
  int ne = bbase[b + 1] - ebeg;
  if (ne > BCAP) ne = BCAP;  // statistically unreachable
  for (int i = t; i < ne; i += 256) se[i] = ebuf[ebeg + i];
  cnt[t] = 0;
  __syncthreads();
  for (int i = t; i < ne; i += 256) atomicAdd(&cnt[se[i] >> 20], 1);
  __syncthreads();
  const int c = cnt[t];
  const int p = (c + 7) & ~7;  // padded size
  sc[t] = p;
  __syncthreads();
  for (int off = 1; off < BN; off <<= 1) {
    int xx = (t >= off) ? sc[t - off] : 0;
    __syncthreads();
    sc[t] += xx;
    __syncthreads();
  }
  const int pexcl = sc[t] - p;
  const int P = sc[BN - 1];  // padded bucket total
  if (t == 0) sbase = atomicAdd(padCur, P);
  pex[t] = pexcl;
  cnt[t] = 0;
  __syncthreads();
  const int n = nbeg + t;
  if (n < N) {
    rowp[n] = sbase + pexcl;
    rowe[n] = sbase + pexcl + p;
  }
  // pad entries -> zero row N
  for (int i = c; i < p; ++i) ss[pexcl + i] = N;
  // bucket-local sort by node
  for (int i = t; i < ne; i += 256) {
    unsigned e = se[i];
    int dL = e >> 20;
    int off = atomicAdd(&cnt[dL], 1);
    ss[pex[dL] + off] = (int)(e & 0xFFFFF);
  }
  __syncthreads();
  // coalesced writeout
  for (int i = t; i < P; i += 256) ssrc[sbase + i] = ss[i];
}

// All-3-layers Wp fold + fp16 MFMA-fragment pack, gate-major.
// Per layer: idx = (((w*4+g)*4+t)*64+lane)*8+i holds
// B[32t + 8*(lane>>4) + i][gate g, col 16w + (lane&15)],
// B[k][g,j] = (k<64) ? Wp[64g'+j][k] : whh[64g''+j][k-64]
//   g=0: r (Wp j ; whh j),  g=1: z (Wp 64+j ; whh 64+j),
//   g=2: inn (Wp 128+j ; 0),  g=3: hn (0 ; whh 128+j)
// Wp[r][k] = sum_m wih[r][m] * ggc[k][m].
__global__ __launch_bounds__(256) void k_wpack3(const float* __restrict__ wih_all,
                                                const float* __restrict__ ggc_all,
                                                const float* __restrict__ whh_all,
                                                _Float16* __restrict__ Bp) {
  int l = blockIdx.x >> 4;  // layer
  int tid = (blockIdx.x & 15) * 256 + threadIdx.x;
  const float* wih = wih_all + (size_t)l * 192 * 64;
  const float* ggc = ggc_all + (size_t)l * 64 * 64;
  const float* whh = whh_all + (size_t)l * 192 * 64;
  int lane = tid & 63;
  int t = (tid >> 6) & 3;
  int wg = tid >> 8;
  int g = wg & 3, w = wg >> 2;
  int j = 16 * w + (lane & 15);
  int kbase = t * 32 + (lane >> 4) * 8;
  _Float16 hv[8];
#pragma unroll
  for (int i = 0; i < 8; ++i) {
    int k = kbase + i;
    float v = 0.0f;
    if (k < 64) {
      if (g < 3) {
        const float* a = wih + (size_t)(g * 64 + j) * 64;
        const float* bp = ggc + (size_t)k * 64;
        float s = 0.0f;
#pragma unroll
        for (int m = 0; m < 64; ++m) s += a[m] * bp[m];
        v = s;
      }
    } else {
      if (g != 2) {
        int row = (g == 3 ? 2 : g) * 64 + j;
        v = whh[(size_t)row * 64 + (k - 64)];
      }
    }
    hv[i] = (_Float16)v;
  }
  _Float16* o = Bp + (size_t)l * 32768 + (size_t)tid * 8;
#pragma unroll
  for (int i = 0; i < 8; ++i) o[i] = hv[i];
}

__device__ __forceinline__ h8v f32lds_to_h8(const float* __restrict__ p) {
  f4v x0 = *(const f4v*)p;
  f4v x1 = *(const f4v*)(p + 4);
  h8v r;
#pragma unroll
  for (int i = 0; i < 4; ++i) {
    r[i] = (_Float16)x0[i];
    r[4 + i] = (_Float16)x1[i];
  }
  return r;
}

#define FSTRIDE 68  // f32 LDS row stride (64 + 4 pad)
#define HSTRIDE 72  // fp16 LDS row stride (64 + 8 pad)

// Fused CSR-gather + GRU (fp16 MFMA, gate-major, in-register gates),
// fp16-only h plane, coalesced stores via LDS exchange.
// Gather: padded edge lists (x8, pads -> zero row N), uniform 8-deep rounds
// with SOFTWARE-PIPELINED index loads (round k+1 idx prefetched while round
// k rows are in flight -> per-round chain = row latency only).
// (256,4): proven config -- tighter bounds make the allocator restructure.
// last=1: fused mean-pool accumulate instead of h stores.
__global__ __launch_bounds__(256, 4) void k_gfu(const _Float16* __restrict__ hin16,
                                                _Float16* __restrict__ hout16,
                                                const int* __restrict__ rowp,
                                                const int* __restrict__ rowe,
                                                const int* __restrict__ ssrc,
                                                const _Float16* __restrict__ Bp,
                                                const float* __restrict__ bih,
                                                const float* __restrict__ bhh,
                                                const int* __restrict__ batch,
                                                float* __restrict__ psum,
                                                float* __restrict__ pcnt,
                                                int N, int nTiles, int last) {
  __shared__ float aggLds[16 * FSTRIDE];
  __shared__ _Float16 hLds[16 * HSTRIDE];
  __shared__ _Float16 oLds[16 * HSTRIDE];
  const int lane = threadIdx.x & 63;
  const int w = threadIdx.x >> 6;
  const int r15 = lane & 15;
  const int kg8 = (lane >> 4) * 8;
  const int jj = w * 16 + r15;  // this lane's output column

  const float b_r = bih[jj] + bhh[jj];
  const float b_z = bih[64 + jj] + bhh[64 + jj];
  const float b_i = bih[128 + jj];
  const float b_h = bhh[128 + jj];

  // B fragments (zero blocks skipped): g=0,1: t=0..3 ; g=2: t=0,1 ; g=3: t=2,3
  h8v b0[4], b1[4], b2[2], b3[2];
#pragma unroll
  for (int t = 0; t < 4; ++t) {
    b0[t] = *(const h8v*)(Bp + ((size_t)((w * 4 + 0) * 4 + t) * 64 + lane) * 8);
    b1[t] = *(const h8v*)(Bp + ((size_t)((w * 4 + 1) * 4 + t) * 64 + lane) * 8);
  }
#pragma unroll
  for (int t = 0; t < 2; ++t) {
    b2[t] = *(const h8v*)(Bp + ((size_t)((w * 4 + 2) * 4 + t) * 64 + lane) * 8);
    b3[t] = *(const h8v*)(Bp + ((size_t)((w * 4 + 3) * 4 + (2 + t)) * 64 + lane) * 8);
  }

  for (int tile = blockIdx.x; tile < nTiles; tile += gridDim.x) {
    const int n0 = tile * 16;
    __syncthreads();  // prev store phase done before restaging
    // ---- gather + fp16 h staging (each 16-lane group owns a node) ----
    {
      const int g = lane >> 4;
      const int node = 4 * w + g;
      const int n = n0 + node;
      const int nc = min(n, N - 1);
      h4v hv = *(const h4v*)(hin16 + (size_t)nc * 64 + 4 * r15);
      f4v a0 = {0, 0, 0, 0}, a1 = {0, 0, 0, 0}, a2 = {0, 0, 0, 0}, a3 = {0, 0, 0, 0};
      if (n < N) {
        int e = rowp[n];
        const int end = rowe[n];
        if (e < end) {
          // prologue: first idx batch
          int i0 = ssrc[e], i1 = ssrc[e + 1], i2 = ssrc[e + 2], i3 = ssrc[e + 3];
          int i4 = ssrc[e + 4], i5 = ssrc[e + 5], i6 = ssrc[e + 6], i7 = ssrc[e + 7];
          do {
            const int ne = e + 8;
            // rows for current batch (8 independent 128B loads)
            h4v v0 = *(const h4v*)(hin16 + (size_t)i0 * 64 + 4 * r15);
            h4v v1 = *(const h4v*)(hin16 + (size_t)i1 * 64 + 4 * r15);
            h4v v2 = *(const h4v*)(hin16 + (size_t)i2 * 64 + 4 * r15);
            h4v v3 = *(const h4v*)(hin16 + (size_t)i3 * 64 + 4 * r15);
            h4v v4 = *(const h4v*)(hin16 + (size_t)i4 * 64 + 4 * r15);
            h4v v5 = *(const h4v*)(hin16 + (size_t)i5 * 64 + 4 * r15);
            h4v v6 = *(const h4v*)(hin16 + (size_t)i6 * 64 + 4 * r15);
            h4v v7 = *(const h4v*)(hin16 + (size_t)i7 * 64 + 4 * r15);
            // prefetch next idx batch (independent of v*)
            if (ne < end) {
              i0 = ssrc[ne]; i1 = ssrc[ne + 1]; i2 = ssrc[ne + 2]; i3 = ssrc[ne + 3];
              i4 = ssrc[ne + 4]; i5 = ssrc[ne + 5]; i6 = ssrc[ne + 6]; i7 = ssrc[ne + 7];
            }
            a0 += __builtin_convertvector(v0, f4v);
            a1 += __builtin_convertvector(v1, f4v);
            a2 += __builtin_convertvector(v2, f4v);
            a3 += __builtin_convertvector(v3, f4v);
            a0 += __builtin_convertvector(v4, f4v);
            a1 += __builtin_convertvector(v5, f4v);
            a2 += __builtin_convertvector(v6, f4v);
            a3 += __builtin_convertvector(v7, f4v);
            e = ne;
          } while (e < end);
        }
      }
      a0 += a1; a2 += a3; a0 += a2;
      *(f4v*)(aggLds + node * FSTRIDE + 4 * r15) = a0;
      *(h4v*)(hLds + node * HSTRIDE + 4 * r15) = hv;
    }
    __syncthreads();

    // ---- A fragments: t=0,1 from agg (f32->fp16), t=2,3 direct fp16 ----
    h8v ah[4];
#pragma unroll
    for (int t = 0; t < 2; ++t)
      ah[t] = f32lds_to_h8(aggLds + r15 * FSTRIDE + t * 32 + kg8);
#pragma unroll
    for (int t = 0; t < 2; ++t)
      ah[2 + t] = *(const h8v*)(hLds + r15 * HSTRIDE + t * 32 + kg8);

    f4v acc0 = {0, 0, 0, 0}, acc1 = {0, 0, 0, 0}, acc2 = {0, 0, 0, 0}, acc3 = {0, 0, 0, 0};
#pragma unroll
    for (int t = 0; t < 4; ++t) {
      acc0 = __builtin_amdgcn_mfma_f32_16x16x32_f16(ah[t], b0[t], acc0, 0, 0, 0);
      acc1 = __builtin_amdgcn_mfma_f32_16x16x32_f16(ah[t], b1[t], acc1, 0, 0, 0);
    }
    acc2 = __builtin_amdgcn_mfma_f32_16x16x32_f16(ah[0], b2[0], acc2, 0, 0, 0);
    acc2 = __builtin_amdgcn_mfma_f32_16x16x32_f16(ah[1], b2[1], acc2, 0, 0, 0);
    acc3 = __builtin_amdgcn_mfma_f32_16x16x32_f16(ah[2], b3[0], acc3, 0, 0, 0);
    acc3 = __builtin_amdgcn_mfma_f32_16x16x32_f16(ah[3], b3[1], acc3, 0, 0, 0);

    // ---- in-register gates: C row = (lane>>4)*4 + q, col = jj [m89] ----
    const int rb = (lane >> 4) * 4;
#pragma unroll
    for (int q = 0; q < 4; ++q) {
      int row = rb + q;
      float hold = (float)hLds[row * HSTRIDE + jj];
      float r = sigmoidf_(acc0[q] + b_r);
      float z = sigmoidf_(acc1[q] + b_z);
      float nv = tanhf_(acc2[q] + b_i + r * (acc3[q] + b_h));
      float o = (1.0f - z) * nv + z * hold;
      oLds[row * HSTRIDE + jj] = (_Float16)fmaxf(o, 0.0f);
    }
    __syncthreads();

    // ---- store phase ----
    if (!last) {
      // coalesced full-row stores: 16 threads cover one 128B fp16 row
      const int node = threadIdx.x >> 4;
      const int ci = (threadIdx.x & 15) * 4;
      const int n = n0 + node;
      if (n < N) {
        h4v o = *(const h4v*)(oLds + node * HSTRIDE + ci);
        *(h4v*)(hout16 + (size_t)n * 64 + ci) = o;
      }
    } else {
      // fused segment-mean accumulate (batch sorted): wave 0 walks the tile
      if (threadIdx.x < 64) {
        int curb = batch[n0];
        float acc = 0.0f, ca = 0.0f;
#pragma unroll 1
        for (int i = 0; i < 16; ++i) {
          int n = n0 + i;
          if (n >= N) break;
          int b = batch[n];
          if (b != curb) {
            atomicAdd(&psum[curb * 64 + lane], acc);
            if (lane == 0) atomicAdd(&pcnt[curb], ca);
            acc = 0.0f; ca = 0.0f; curb = b;
          }
          acc += (float)oLds[i * HSTRIDE + lane];
          ca += 1.0f;
        }
        atomicAdd(&psum[curb * 64 + lane], acc);
        if (lane == 0) atomicAdd(&pcnt[curb], ca);
      }
    }
  }
}

// MLP head: 64 -> 32 -> 16 -> 1, one 64-thread block per batch element
__global__ __launch_bounds__(64) void k_head(const float* __restrict__ psum,
                                             const float* __restrict__ pcnt,
                                             const float* __restrict__ fc1W,
                                             const float* __restrict__ fc1b,
                                             const float* __restrict__ fc2W,
                                             const float* __restrict__ fc2b,
                                             const float* __restrict__ fc3W,
                                             const float* __restrict__ fc3b,
                                             float* __restrict__ out) {
  int b = blockIdx.x;
  int j = threadIdx.x;
  float c = fmaxf(pcnt[b], 1.0f);
  float p = psum[b * 64 + j] / c;
  int j1 = j & 31;
  float y1 = fc1b[j1];
#pragma unroll
  for (int k = 0; k < 64; ++k) y1 += fc1W[j1 * 64 + k] * __shfl(p, k, 64);
  y1 = fmaxf(y1, 0.0f);
  int j2 = j & 15;
  float y2 = fc2b[j2];
#pragma unroll
  for (int k = 0; k < 32; ++k) y2 += fc2W[j2 * 32 + k] * __shfl(y1, k, 64);
  y2 = fmaxf(y2, 0.0f);
  float y = 0.0f;
#pragma unroll
  for (int k = 0; k < 16; ++k) y += fc3W[k] * __shfl(y2, k, 64);
  if (j == 0) out[b] = y + fc3b[0];
}

extern "C" void kernel_launch(void* const* d_in, const int* in_sizes, int n_in,
                              void* d_out, int out_size, void* d_ws, size_t ws_size,
                              hipStream_t stream) {
  const int N = in_sizes[0];
  const int E = in_sizes[1] / 2;
  const int B = out_size;

  const int* x = (const int*)d_in[0];
  const int* eidx = (const int*)d_in[1];
  const int* batch = (const int*)d_in[3];
  const float* emb = (const float*)d_in[4];
  const float* ggcW = (const float*)d_in[7];
  const float* wih = (const float*)d_in[8];
  const float* whh = (const float*)d_in[9];
  const float* bih = (const float*)d_in[10];
  const float* bhh = (const float*)d_in[11];
  const float* fc1W = (const float*)d_in[12];
  const float* fc1b = (const float*)d_in[13];
  const float* fc2W = (const float*)d_in[14];
  const float* fc2b = (const float*)d_in[15];
  const float* fc3W = (const float*)d_in[16];
  const float* fc3b = (const float*)d_in[17];
  float* out = (float*)d_out;

  const int* srcp = eidx;
  const int* dstp = eidx + E;
  const int nb = (N + BN - 1) / BN;  // buckets

  char* ws = (char*)d_ws;
  size_t off = 0;
  auto alloc = [&](size_t bytes) -> void* {
    void* p = ws + off;
    off = (off + bytes + 255) & ~(size_t)255;
    return p;
  };
  _Float16* h16a = (_Float16*)alloc((size_t)(N + 1) * 64 * 2);
  _Float16* h16b = (_Float16*)alloc((size_t)(N + 1) * 64 * 2);
  int* rowp = (int*)alloc((size_t)(N + 1) * 4);
  int* rowe = (int*)alloc((size_t)(N + 1) * 4);
  int* ssrc = (int*)alloc(((size_t)E + 8 * (size_t)N) * 4);  // padded
  unsigned* ebuf = (unsigned*)alloc((size_t)E * 4);
  int* bbase = (int*)alloc((size_t)(NBMAX + 1) * 4);
  // contiguous zero region: hist | cursor | padCur | pool -> zeroed by k_embed
  size_t zbeg = off;
  int* hist = (int*)alloc((size_t)NBMAX * 4);
  int* cursor = (int*)alloc((size_t)NBMAX * 4);
  int* padCur = (int*)alloc(256);
  float* pool = (float*)alloc((size_t)(B * 64 + B) * 4);
  size_t zend = off;
  float* psum = pool;
  float* pcnt = pool + (size_t)B * 64;
  _Float16* Bp = (_Float16*)alloc((size_t)3 * 32768 * 2);
  const int zwords = (int)((zend - zbeg) / 4);

  // NOTE: k_embed zeroes hist (first zwords threads) BEFORE its own hist
  // accumulation within the same kernel -- but zbuf zeroing and LDS-hist
  // flush are both in k_embed. Block 0..511 flush AFTER zeroing their own
  // idx range; cross-block ordering hazard: a block could flush lh into
  // hist before another block zeroes that word. Avoid by zeroing hist in
  // its own earlier tiny kernel? Instead: zero region EXCLUDES hist -- we
  // pre-zero hist via the first 512 blocks' lh path reading hist=0 is not
  // needed since hist is written with atomicAdd. Resolve: zero hist in
  // k_bscan? Simplest correct: keep hist in zbuf but have k_embed's hist
  // flush go to a SEPARATE accumulator... -- we instead zero hist with a
  // dedicated memset below (cheap, one dispatch), zbuf covers the rest.
  hipMemsetAsync(hist, 0, (size_t)NBMAX * 4, stream);
  k_embed<<<((N + 1) * 64 + 255) / 256, 256, 0, stream>>>(
      x, emb, h16a, h16b, (int*)(ws + zbeg + NBMAX * 4), zwords - NBMAX, dstp,
      hist, N, E);
  k_bscan<<<1, 1024, 0, stream>>>(hist, bbase, nb);
  k_scatter<<<(E + EPB - 1) / EPB, 256, 0, stream>>>(srcp, dstp, bbase, cursor,
                                                     ebuf, E, nb);
  k_csr<<<nb, 256, 0, stream>>>(ebuf, bbase, padCur, rowp, rowe, ssrc, N);
  k_wpack3<<<48, 256, 0, stream>>>(wih, ggcW, whh, Bp);

  const int nTiles = (N + 15) / 16;
  const int grid = nTiles < 2048 ? nTiles : 2048;
  _Float16* hh[2] = {h16a, h16b};
  for (int l = 0; l < 3; ++l) {
    int a = l & 1, b = 1 - a;
    k_gfu<<<grid, 256, 0, stream>>>(hh[a], hh[b], rowp, rowe, ssrc,
                                    Bp + (size_t)l * 32768,
                                    bih + (size_t)l * 192, bhh + (size_t)l * 192,
                                    batch, psum, pcnt, N, nTiles, l == 2 ? 1 : 0);
  }

  k_head<<<B, 64, 0, stream>>>(psum, pcnt, fc1W, fc1b, fc2W, fc2b, fc3W, fc3b, out);
}

// Round 16
// 195.436 us; speedup vs baseline: 1.7424x; 1.0399x over previous
//
#include <hip/hip_runtime.h>
#include <cstdint>

using h8v = __attribute__((ext_vector_type(8))) _Float16;
using h4v = __attribute__((ext_vector_type(4))) _Float16;
using f4v = __attribute__((ext_vector_type(4))) float;

__device__ __forceinline__ float sigmoidf_(float x) {
  return 1.0f / (1.0f + __expf(-x));
}
__device__ __forceinline__ float tanhf_(float x) {
  return 2.0f / (1.0f + __expf(-2.0f * x)) - 1.0f;
}

#define BN 256       // nodes per bucket
#define BCAP 4096    // LDS edge buffer cap (raw avg 2560/bucket)
#define NBMAX 1024   // max buckets (N <= 262144)

// Fused preamble kernel:
//  - all blocks: h16a[i][j] = emb[x[i]][j]; row N of both planes = 0
//  - all blocks: zero the scratch region (cursor|padCur|pool)
//  - blocks <512: LDS-aggregated bucket histogram of dst (bucket = dst>>8)
//  - blocks 512..559: the 3-layer Wp fold + fp16 MFMA-fragment pack
__global__ __launch_bounds__(256) void k_embed(const int* __restrict__ x,
                                               const float* __restrict__ emb,
                                               _Float16* __restrict__ h16a,
                                               _Float16* __restrict__ h16b,
                                               int* __restrict__ zbuf, int zwords,
                                               const int* __restrict__ dst,
                                               int* __restrict__ hist,
                                               const float* __restrict__ wih_all,
                                               const float* __restrict__ ggc_all,
                                               const float* __restrict__ whh_all,
                                               _Float16* __restrict__ Bp,
                                               int N, int E) {
  __shared__ int lh[NBMAX];
  int idx = blockIdx.x * 256 + threadIdx.x;
  if (idx < zwords) zbuf[idx] = 0;
  if (idx < (N + 1) * 64) {
    int i = idx >> 6, j = idx & 63;
    if (i < N) {
      h16a[idx] = (_Float16)emb[x[i] * 64 + j];
    } else {
      h16a[idx] = (_Float16)0.0f;
      h16b[idx] = (_Float16)0.0f;
    }
  }
  if (blockIdx.x < 512) {
    for (int i = threadIdx.x; i < NBMAX; i += 256) lh[i] = 0;
    __syncthreads();
    for (int e = blockIdx.x * 256 + threadIdx.x; e < E; e += 512 * 256)
      atomicAdd(&lh[dst[e] >> 8], 1);
    __syncthreads();
    for (int i = threadIdx.x; i < NBMAX; i += 256)
      if (lh[i]) atomicAdd(&hist[i], lh[i]);
  } else if (blockIdx.x < 560) {
    // weight pack: gate-major fragments, Wp = wih @ ggc^T fold.
    // frag idx = (((w*4+g)*4+t)*64+lane)*8+i holds
    // B[32t+8*(lane>>4)+i][gate g, col 16w+(lane&15)]
    int wb = blockIdx.x - 512;
    int l = wb >> 4;
    int tid = (wb & 15) * 256 + threadIdx.x;
    const float* wih = wih_all + (size_t)l * 192 * 64;
    const float* ggc = ggc_all + (size_t)l * 64 * 64;
    const float* whh = whh_all + (size_t)l * 192 * 64;
    int lane = tid & 63;
    int t = (tid >> 6) & 3;
    int wg = tid >> 8;
    int g = wg & 3, w = wg >> 2;
    int j = 16 * w + (lane & 15);
    int kbase = t * 32 + (lane >> 4) * 8;
    _Float16 hv[8];
#pragma unroll
    for (int i = 0; i < 8; ++i) {
      int k = kbase + i;
      float v = 0.0f;
      if (k < 64) {
        if (g < 3) {
          const float* a = wih + (size_t)(g * 64 + j) * 64;
          const float* bp = ggc + (size_t)k * 64;
          float s = 0.0f;
#pragma unroll
          for (int m = 0; m < 64; ++m) s += a[m] * bp[m];
          v = s;
        }
      } else {
        if (g != 2) {
          int row = (g == 3 ? 2 : g) * 64 + j;
          v = whh[(size_t)row * 64 + (k - 64)];
        }
      }
      hv[i] = (_Float16)v;
    }
    _Float16* o = Bp + (size_t)l * 32768 + (size_t)tid * 8;
#pragma unroll
    for (int i = 0; i < 8; ++i) o[i] = hv[i];
  }
}

#define EPB 4096
// scatter edges into bucket-major chunks: ebuf[pos] = (dstLocal<<20) | src.
// Each block recomputes the 1024-bucket exclusive scan of hist in LDS
// (replaces the separate k_bscan dispatch + bbase buffer).
__global__ __launch_bounds__(256) void k_scatter(const int* __restrict__ src,
                                                 const int* __restrict__ dst,
                                                 const int* __restrict__ hist,
                                                 int* __restrict__ cursor,
                                                 unsigned* __restrict__ ebuf,
                                                 int E, int nb) {
  __shared__ int lh[NBMAX];
  __shared__ int sbb[NBMAX];
  __shared__ int tmp[256];
  const int t = threadIdx.x;
  // ---- exclusive scan of hist[0..1024) -> sbb (hist is 0 beyond nb) ----
  int h0 = hist[4 * t], h1 = hist[4 * t + 1], h2 = hist[4 * t + 2], h3 = hist[4 * t + 3];
  int s = h0 + h1 + h2 + h3;
  tmp[t] = s;
  __syncthreads();
  for (int off = 1; off < 256; off <<= 1) {
    int xx = (t >= off) ? tmp[t - off] : 0;
    __syncthreads();
    tmp[t] += xx;
    __syncthreads();
  }
  int excl = tmp[t] - s;
  sbb[4 * t] = excl;
  sbb[4 * t + 1] = excl + h0;
  sbb[4 * t + 2] = excl + h0 + h1;
  sbb[4 * t + 3] = excl + h0 + h1 + h2;
  for (int i = t; i < NBMAX; i += 256) lh[i] = 0;
  __syncthreads();
  // ---- local histogram, chunk reservation, packed scatter ----
  const int e0 = blockIdx.x * EPB;
  const int e1 = min(e0 + EPB, E);
  for (int e = e0 + t; e < e1; e += 256) atomicAdd(&lh[dst[e] >> 8], 1);
  __syncthreads();
  for (int i = t; i < nb; i += 256) {
    int c = lh[i];
    if (c) lh[i] = sbb[i] + atomicAdd(&cursor[i], c);
  }
  __syncthreads();
  // NOTE: lh[i] now holds this block's write base for bucket i (if c>0);
  // reuse sbb as the running offset counter.
  for (int i = t; i < NBMAX; i += 256) sbb[i] = 0;
  __syncthreads();
  for (int e = e0 + t; e < e1; e += 256) {
    int d = dst[e];
    int b = d >> 8;
    int off = atomicAdd(&sbb[b], 1);
    ebuf[lh[b] + off] = ((unsigned)(d & 255) << 20) | (unsigned)src[e];
  }
}

// per-bucket padded CSR: per-node counts, pad to multiple of 8 with src=N
// (zero row), reserve padded region via global cursor, emit rowp/rowe/ssrc.
// Bucket base recomputed as a reduction over hist[0..b); ne = hist[b].
__global__ __launch_bounds__(256) void k_csr(const unsigned* __restrict__ ebuf,
                                             const int* __restrict__ hist,
                                             int* __restrict__ padCur,
                                             int* __restrict__ rowp,
                                             int* __restrict__ rowe,
                                             int* __restrict__ ssrc, int N) {
  __shared__ unsigned se[BCAP];
  __shared__ int ss[BCAP];
  __shared__ int cnt[BN], pex[BN], sc[BN];
  __shared__ int red[256];
  __shared__ int sbase;
  const int b = blockIdx.x;
  const int t = threadIdx.x;
  const int nbeg = b * BN;
  // ---- ebeg = sum(hist[0..b)) ----
  int local = 0;
  for (int i = t; i < b; i += 256) local += hist[i];
  red[t] = local;
  __syncthreads();
  for (int off = 128; off > 0; off >>= 1) {
    if (t < off) red[t] += red[t + off];
    __syncthreads();
  }
  const int ebeg = red[0];
  int ne = hist[b];
  if (ne > BCAP) ne = BCAP;  // statistically unreachable
  for (int i = t; i < ne; i += 256) se[i] = ebuf[ebeg + i];
  cnt[t] = 0;
  __syncthreads();
  for (int i = t; i < ne; i += 256) atomicAdd(&cnt[se[i] >> 20], 1);
  __syncthreads();
  const int c = cnt[t];
  const int p = (c + 7) & ~7;  // padded size
  sc[t] = p;
  __syncthreads();
  for (int off = 1; off < BN; off <<= 1) {
    int xx = (t >= off) ? sc[t - off] : 0;
    __syncthreads();
    sc[t] += xx;
    __syncthreads();
  }
  const int pexcl = sc[t] - p;
  const int P = sc[BN - 1];  // padded bucket total
  if (t == 0) sbase = atomicAdd(padCur, P);
  pex[t] = pexcl;
  cnt[t] = 0;
  __syncthreads();
  const int n = nbeg + t;
  if (n < N) {
    rowp[n] = sbase + pexcl;
    rowe[n] = sbase + pexcl + p;
  }
  // pad entries -> zero row N
  for (int i = c; i < p; ++i) ss[pexcl + i] = N;
  // bucket-local sort by node
  for (int i = t; i < ne; i += 256) {
    unsigned e = se[i];
    int dL = e >> 20;
    int off = atomicAdd(&cnt[dL], 1);
    ss[pex[dL] + off] = (int)(e & 0xFFFFF);
  }
  __syncthreads();
  // coalesced writeout
  for (int i = t; i < P; i += 256) ssrc[sbase + i] = ss[i];
}

__device__ __forceinline__ h8v f32lds_to_h8(const float* __restrict__ p) {
  f4v x0 = *(const f4v*)p;
  f4v x1 = *(const f4v*)(p + 4);
  h8v r;
#pragma unroll
  for (int i = 0; i < 4; ++i) {
    r[i] = (_Float16)x0[i];
    r[4 + i] = (_Float16)x1[i];
  }
  return r;
}

#define FSTRIDE 68  // f32 LDS row stride (64 + 4 pad)
#define HSTRIDE 72  // fp16 LDS row stride (64 + 8 pad)

// Fused CSR-gather + GRU (fp16 MFMA, gate-major, in-register gates),
// fp16-only h plane, coalesced stores via LDS exchange.
// Gather: padded edge lists (x8, pads -> zero row N), uniform 8-deep rounds
// with software-pipelined index loads. (256,4): proven config -- tighter
// bounds make the allocator restructure (r6: 40 VGPR sink; r12: 32+spill).
// last=1: fused mean-pool accumulate instead of h stores.
__global__ __launch_bounds__(256, 4) void k_gfu(const _Float16* __restrict__ hin16,
                                                _Float16* __restrict__ hout16,
                                                const int* __restrict__ rowp,
                                                const int* __restrict__ rowe,
                                                const int* __restrict__ ssrc,
                                                const _Float16* __restrict__ Bp,
                                                const float* __restrict__ bih,
                                                const float* __restrict__ bhh,
                                                const int* __restrict__ batch,
                                                float* __restrict__ psum,
                                                float* __restrict__ pcnt,
                                                int N, int nTiles, int last) {
  __shared__ float aggLds[16 * FSTRIDE];
  __shared__ _Float16 hLds[16 * HSTRIDE];
  __shared__ _Float16 oLds[16 * HSTRIDE];
  const int lane = threadIdx.x & 63;
  const int w = threadIdx.x >> 6;
  const int r15 = lane & 15;
  const int kg8 = (lane >> 4) * 8;
  const int jj = w * 16 + r15;  // this lane's output column

  const float b_r = bih[jj] + bhh[jj];
  const float b_z = bih[64 + jj] + bhh[64 + jj];
  const float b_i = bih[128 + jj];
  const float b_h = bhh[128 + jj];

  // B fragments (zero blocks skipped): g=0,1: t=0..3 ; g=2: t=0,1 ; g=3: t=2,3
  h8v b0[4], b1[4], b2[2], b3[2];
#pragma unroll
  for (int t = 0; t < 4; ++t) {
    b0[t] = *(const h8v*)(Bp + ((size_t)((w * 4 + 0) * 4 + t) * 64 + lane) * 8);
    b1[t] = *(const h8v*)(Bp + ((size_t)((w * 4 + 1) * 4 + t) * 64 + lane) * 8);
  }
#pragma unroll
  for (int t = 0; t < 2; ++t) {
    b2[t] = *(const h8v*)(Bp + ((size_t)((w * 4 + 2) * 4 + t) * 64 + lane) * 8);
    b3[t] = *(const h8v*)(Bp + ((size_t)((w * 4 + 3) * 4 + (2 + t)) * 64 + lane) * 8);
  }

  for (int tile = blockIdx.x; tile < nTiles; tile += gridDim.x) {
    const int n0 = tile * 16;
    __syncthreads();  // prev store phase done before restaging
    // ---- gather + fp16 h staging (each 16-lane group owns a node) ----
    {
      const int g = lane >> 4;
      const int node = 4 * w + g;
      const int n = n0 + node;
      const int nc = min(n, N - 1);
      h4v hv = *(const h4v*)(hin16 + (size_t)nc * 64 + 4 * r15);
      f4v a0 = {0, 0, 0, 0}, a1 = {0, 0, 0, 0}, a2 = {0, 0, 0, 0}, a3 = {0, 0, 0, 0};
      if (n < N) {
        int e = rowp[n];
        const int end = rowe[n];
        if (e < end) {
          // prologue: first idx batch
          int i0 = ssrc[e], i1 = ssrc[e + 1], i2 = ssrc[e + 2], i3 = ssrc[e + 3];
          int i4 = ssrc[e + 4], i5 = ssrc[e + 5], i6 = ssrc[e + 6], i7 = ssrc[e + 7];
          do {
            const int ne = e + 8;
            // rows for current batch (8 independent 128B loads)
            h4v v0 = *(const h4v*)(hin16 + (size_t)i0 * 64 + 4 * r15);
            h4v v1 = *(const h4v*)(hin16 + (size_t)i1 * 64 + 4 * r15);
            h4v v2 = *(const h4v*)(hin16 + (size_t)i2 * 64 + 4 * r15);
            h4v v3 = *(const h4v*)(hin16 + (size_t)i3 * 64 + 4 * r15);
            h4v v4 = *(const h4v*)(hin16 + (size_t)i4 * 64 + 4 * r15);
            h4v v5 = *(const h4v*)(hin16 + (size_t)i5 * 64 + 4 * r15);
            h4v v6 = *(const h4v*)(hin16 + (size_t)i6 * 64 + 4 * r15);
            h4v v7 = *(const h4v*)(hin16 + (size_t)i7 * 64 + 4 * r15);
            // prefetch next idx batch (independent of v*)
            if (ne < end) {
              i0 = ssrc[ne]; i1 = ssrc[ne + 1]; i2 = ssrc[ne + 2]; i3 = ssrc[ne + 3];
              i4 = ssrc[ne + 4]; i5 = ssrc[ne + 5]; i6 = ssrc[ne + 6]; i7 = ssrc[ne + 7];
            }
            a0 += __builtin_convertvector(v0, f4v);
            a1 += __builtin_convertvector(v1, f4v);
            a2 += __builtin_convertvector(v2, f4v);
            a3 += __builtin_convertvector(v3, f4v);
            a0 += __builtin_convertvector(v4, f4v);
            a1 += __builtin_convertvector(v5, f4v);
            a2 += __builtin_convertvector(v6, f4v);
            a3 += __builtin_convertvector(v7, f4v);
            e = ne;
          } while (e < end);
        }
      }
      a0 += a1; a2 += a3; a0 += a2;
      *(f4v*)(aggLds + node * FSTRIDE + 4 * r15) = a0;
      *(h4v*)(hLds + node * HSTRIDE + 4 * r15) = hv;
    }
    __syncthreads();

    // ---- A fragments: t=0,1 from agg (f32->fp16), t=2,3 direct fp16 ----
    h8v ah[4];
#pragma unroll
    for (int t = 0; t < 2; ++t)
      ah[t] = f32lds_to_h8(aggLds + r15 * FSTRIDE + t * 32 + kg8);
#pragma unroll
    for (int t = 0; t < 2; ++t)
      ah[2 + t] = *(const h8v*)(hLds + r15 * HSTRIDE + t * 32 + kg8);

    f4v acc0 = {0, 0, 0, 0}, acc1 = {0, 0, 0, 0}, acc2 = {0, 0, 0, 0}, acc3 = {0, 0, 0, 0};
#pragma unroll
    for (int t = 0; t < 4; ++t) {
      acc0 = __builtin_amdgcn_mfma_f32_16x16x32_f16(ah[t], b0[t], acc0, 0, 0, 0);
      acc1 = __builtin_amdgcn_mfma_f32_16x16x32_f16(ah[t], b1[t], acc1, 0, 0, 0);
    }
    acc2 = __builtin_amdgcn_mfma_f32_16x16x32_f16(ah[0], b2[0], acc2, 0, 0, 0);
    acc2 = __builtin_amdgcn_mfma_f32_16x16x32_f16(ah[1], b2[1], acc2, 0, 0, 0);
    acc3 = __builtin_amdgcn_mfma_f32_16x16x32_f16(ah[2], b3[0], acc3, 0, 0, 0);
    acc3 = __builtin_amdgcn_mfma_f32_16x16x32_f16(ah[3], b3[1], acc3, 0, 0, 0);

    // ---- in-register gates: C row = (lane>>4)*4 + q, col = jj [m89] ----
    const int rb = (lane >> 4) * 4;
#pragma unroll
    for (int q = 0; q < 4; ++q) {
      int row = rb + q;
      float hold = (float)hLds[row * HSTRIDE + jj];
      float r = sigmoidf_(acc0[q] + b_r);
      float z = sigmoidf_(acc1[q] + b_z);
      float nv = tanhf_(acc2[q] + b_i + r * (acc3[q] + b_h));
      float o = (1.0f - z) * nv + z * hold;
      oLds[row * HSTRIDE + jj] = (_Float16)fmaxf(o, 0.0f);
    }
    __syncthreads();

    // ---- store phase ----
    if (!last) {
      // coalesced full-row stores: 16 threads cover one 128B fp16 row
      const int node = threadIdx.x >> 4;
      const int ci = (threadIdx.x & 15) * 4;
      const int n = n0 + node;
      if (n < N) {
        h4v o = *(const h4v*)(oLds + node * HSTRIDE + ci);
        *(h4v*)(hout16 + (size_t)n * 64 + ci) = o;
      }
    } else {
      // fused segment-mean accumulate (batch sorted): wave 0 walks the tile
      if (threadIdx.x < 64) {
        int curb = batch[n0];
        float acc = 0.0f, ca = 0.0f;
#pragma unroll 1
        for (int i = 0; i < 16; ++i) {
          int n = n0 + i;
          if (n >= N) break;
          int b = batch[n];
          if (b != curb) {
            atomicAdd(&psum[curb * 64 + lane], acc);
            if (lane == 0) atomicAdd(&pcnt[curb], ca);
            acc = 0.0f; ca = 0.0f; curb = b;
          }
          acc += (float)oLds[i * HSTRIDE + lane];
          ca += 1.0f;
        }
        atomicAdd(&psum[curb * 64 + lane], acc);
        if (lane == 0) atomicAdd(&pcnt[curb], ca);
      }
    }
  }
}

// MLP head: 64 -> 32 -> 16 -> 1, one 64-thread block per batch element
__global__ __launch_bounds__(64) void k_head(const float* __restrict__ psum,
                                             const float* __restrict__ pcnt,
                                             const float* __restrict__ fc1W,
                                             const float* __restrict__ fc1b,
                                             const float* __restrict__ fc2W,
                                             const float* __restrict__ fc2b,
                                             const float* __restrict__ fc3W,
                                             const float* __restrict__ fc3b,
                                             float* __restrict__ out) {
  int b = blockIdx.x;
  int j = threadIdx.x;
  float c = fmaxf(pcnt[b], 1.0f);
  float p = psum[b * 64 + j] / c;
  int j1 = j & 31;
  float y1 = fc1b[j1];
#pragma unroll
  for (int k = 0; k < 64; ++k) y1 += fc1W[j1 * 64 + k] * __shfl(p, k, 64);
  y1 = fmaxf(y1, 0.0f);
  int j2 = j & 15;
  float y2 = fc2b[j2];
#pragma unroll
  for (int k = 0; k < 32; ++k) y2 += fc2W[j2 * 32 + k] * __shfl(y1, k, 64);
  y2 = fmaxf(y2, 0.0f);
  float y = 0.0f;
#pragma unroll
  for (int k = 0; k < 16; ++k) y += fc3W[k] * __shfl(y2, k, 64);
  if (j == 0) out[b] = y + fc3b[0];
}

extern "C" void kernel_launch(void* const* d_in, const int* in_sizes, int n_in,
                              void* d_out, int out_size, void* d_ws, size_t ws_size,
                              hipStream_t stream) {
  const int N = in_sizes[0];
  const int E = in_sizes[1] / 2;
  const int B = out_size;

  const int* x = (const int*)d_in[0];
  const int* eidx = (const int*)d_in[1];
  const int* batch = (const int*)d_in[3];
  const float* emb = (const float*)d_in[4];
  const float* ggcW = (const float*)d_in[7];
  const float* wih = (const float*)d_in[8];
  const float* whh = (const float*)d_in[9];
  const float* bih = (const float*)d_in[10];
  const float* bhh = (const float*)d_in[11];
  const float* fc1W = (const float*)d_in[12];
  const float* fc1b = (const float*)d_in[13];
  const float* fc2W = (const float*)d_in[14];
  const float* fc2b = (const float*)d_in[15];
  const float* fc3W = (const float*)d_in[16];
  const float* fc3b = (const float*)d_in[17];
  float* out = (float*)d_out;

  const int* srcp = eidx;
  const int* dstp = eidx + E;
  const int nb = (N + BN - 1) / BN;  // buckets

  char* ws = (char*)d_ws;
  size_t off = 0;
  auto alloc = [&](size_t bytes) -> void* {
    void* p = ws + off;
    off = (off + bytes + 255) & ~(size_t)255;
    return p;
  };
  _Float16* h16a = (_Float16*)alloc((size_t)(N + 1) * 64 * 2);
  _Float16* h16b = (_Float16*)alloc((size_t)(N + 1) * 64 * 2);
  int* rowp = (int*)alloc((size_t)(N + 1) * 4);
  int* rowe = (int*)alloc((size_t)(N + 1) * 4);
  int* ssrc = (int*)alloc(((size_t)E + 8 * (size_t)N) * 4);  // padded
  unsigned* ebuf = (unsigned*)alloc((size_t)E * 4);
  int* hist = (int*)alloc((size_t)NBMAX * 4);  // zeroed by memset (ordering)
  // contiguous zero region: cursor | padCur | pool -> zeroed inside k_embed
  size_t zbeg = off;
  int* cursor = (int*)alloc((size_t)NBMAX * 4);
  int* padCur = (int*)alloc(256);
  float* pool = (float*)alloc((size_t)(B * 64 + B) * 4);
  size_t zend = off;
  float* psum = pool;
  float* pcnt = pool + (size_t)B * 64;
  _Float16* Bp = (_Float16*)alloc((size_t)3 * 32768 * 2);
  const int zwords = (int)((zend - zbeg) / 4);

  // --- preamble: memset(hist) -> fused embed/hist/wpack -> scatter -> csr ---
  hipMemsetAsync(hist, 0, (size_t)NBMAX * 4, stream);
  k_embed<<<((N + 1) * 64 + 255) / 256, 256, 0, stream>>>(
      x, emb, h16a, h16b, (int*)(ws + zbeg), zwords, dstp, hist,
      wih, ggcW, whh, Bp, N, E);
  k_scatter<<<(E + EPB - 1) / EPB, 256, 0, stream>>>(srcp, dstp, hist, cursor,
                                                     ebuf, E, nb);
  k_csr<<<nb, 256, 0, stream>>>(ebuf, hist, padCur, rowp, rowe, ssrc, N);

  const int nTiles = (N + 15) / 16;
  const int grid = nTiles < 2048 ? nTiles : 2048;
  _Float16* hh[2] = {h16a, h16b};
  for (int l = 0; l < 3; ++l) {
    int a = l & 1, b = 1 - a;
    k_gfu<<<grid, 256, 0, stream>>>(hh[a], hh[b], rowp, rowe, ssrc,
                                    Bp + (size_t)l * 32768,
                                    bih + (size_t)l * 192, bhh + (size_t)l * 192,
                                    batch, psum, pcnt, N, nTiles, l == 2 ? 1 : 0);
  }

  k_head<<<B, 64, 0, stream>>>(psum, pcnt, fc1W, fc1b, fc2W, fc2b, fc3W, fc3b, out);
}